// Round 6
// baseline (858.133 us; speedup 1.0000x reference)
//
#include <hip/hip_runtime.h>
#include <hip/hip_bf16.h>
#include <math.h>

// Problem constants
#define BB 4
#define DMODEL 1024
#define LL 2048
#define DSTATE 16
#define DCONV 4
#define DINNER 2048
#define DTRANK 64
#define BL (BB * LL)          // 8192 rows
#define NCHUNK 32
#define LCH (LL / NCHUNK)     // 64
#define PFPLANE (BB * DINNER * DSTATE)   // 131072 floats per chunk-plane

typedef unsigned short ushort;
typedef __bf16 bf16x8 __attribute__((ext_vector_type(8)));
typedef float f32x4 __attribute__((ext_vector_type(4)));

__device__ inline ushort f2bf(float f) {
    unsigned int u = __float_as_uint(f);
    u += 0x7fffu + ((u >> 16) & 1u);           // round-to-nearest-even
    return (ushort)(u >> 16);
}
__device__ inline float bf2f(ushort h) {
    return __uint_as_float(((unsigned int)h) << 16);
}

// ---------------------------------------------------------------------------
// fp32 -> bf16 bulk convert (n4 = count/4)
// ---------------------------------------------------------------------------
__global__ void f32_to_bf16(const float* __restrict__ src, ushort* __restrict__ dst, int n4) {
    int i = blockIdx.x * 256 + threadIdx.x;
    if (i < n4) {
        float4 v = ((const float4*)src)[i];
        ushort4 o;
        o.x = f2bf(v.x); o.y = f2bf(v.y); o.z = f2bf(v.z); o.w = f2bf(v.w);
        ((ushort4*)dst)[i] = o;
    }
}

// ---------------------------------------------------------------------------
// x (B, DMODEL, L) fp32 -> xtb (B*L, DMODEL) bf16 (transpose + convert)
// ---------------------------------------------------------------------------
__global__ void transpose_convert_x(const float* __restrict__ x, ushort* __restrict__ xtb) {
    __shared__ float tile[32][33];
    int b = blockIdx.z;
    int l0 = blockIdx.x * 32;
    int d0 = blockIdx.y * 32;
    int tx = threadIdx.x, ty = threadIdx.y;       // 32 x 8
    const float* xb = x + (size_t)b * DMODEL * LL;
#pragma unroll
    for (int j = 0; j < 32; j += 8)
        tile[ty + j][tx] = xb[(size_t)(d0 + ty + j) * LL + l0 + tx];
    __syncthreads();
    ushort* xtbb = xtb + (size_t)b * LL * DMODEL;
#pragma unroll
    for (int j = 0; j < 32; j += 8)
        xtbb[(size_t)(l0 + ty + j) * DMODEL + d0 + tx] = f2bf(tile[tx][ty + j]);
}

// ---------------------------------------------------------------------------
// bf16 MFMA GEMM: C(M,N) = A(M,K) @ Bw(N,K)^T, fp32 accumulate.
// 128x128 block tile, 256 threads (4 waves, 2x2), 4x4 MFMA tiles per wave,
// K-tile 32, LDS rows padded to 40 bf16 (2-way conflicts only = free).
// flags: 1 = write fp32 C (ldc), 2 = write bf16 Cb (ldcb, col<nbmax),
//        4 = add bias[col] (fp32), 8 = softplus.
// ---------------------------------------------------------------------------
__global__ __launch_bounds__(256) void gemm_bf16(
    const ushort* __restrict__ A, const ushort* __restrict__ Bw,
    float* __restrict__ C, ushort* __restrict__ Cb,
    const float* __restrict__ bias,
    int M, int N, int K, int lda, int ldb, int ldc, int ldcb, int nbmax, int flags)
{
    __shared__ ushort As[128 * 40];
    __shared__ ushort Bs[128 * 40];
    const int tid = threadIdx.x;
    const int m0 = blockIdx.y * 128;
    const int n0 = blockIdx.x * 128;
    const int srow = tid >> 2;                 // 0..63
    const int sseg = (tid & 3) * 8;            // k offset: 0,8,16,24
    const int wave = tid >> 6;
    const int lane = tid & 63;
    const int wm = (wave >> 1) * 64;
    const int wn = (wave & 1) * 64;
    const int fr = lane & 15;
    const int fq = lane >> 4;                  // quad 0..3
    const int fk = fq * 8;

    f32x4 acc[4][4];
#pragma unroll
    for (int i = 0; i < 4; ++i)
#pragma unroll
        for (int j = 0; j < 4; ++j)
            acc[i][j] = (f32x4)(0.0f);

    const ushort* Ap = A + (size_t)(m0 + srow) * lda + sseg;
    const ushort* Bp = Bw + (size_t)(n0 + srow) * ldb + sseg;
    const bool bv0 = (n0 + srow) < N;
    const bool bv1 = (n0 + srow + 64) < N;

    for (int k0 = 0; k0 < K; k0 += 32) {
        uint4 a0 = *(const uint4*)(Ap + k0);
        uint4 a1 = *(const uint4*)(Ap + (size_t)64 * lda + k0);
        uint4 zz = make_uint4(0u, 0u, 0u, 0u);
        uint4 b0 = bv0 ? *(const uint4*)(Bp + k0) : zz;
        uint4 b1 = bv1 ? *(const uint4*)(Bp + (size_t)64 * ldb + k0) : zz;
        __syncthreads();
        *(uint4*)&As[srow * 40 + sseg] = a0;
        *(uint4*)&As[(srow + 64) * 40 + sseg] = a1;
        *(uint4*)&Bs[srow * 40 + sseg] = b0;
        *(uint4*)&Bs[(srow + 64) * 40 + sseg] = b1;
        __syncthreads();
        bf16x8 af[4], bfr[4];
#pragma unroll
        for (int i = 0; i < 4; ++i)
            af[i] = *(const bf16x8*)&As[(wm + i * 16 + fr) * 40 + fk];
#pragma unroll
        for (int j = 0; j < 4; ++j)
            bfr[j] = *(const bf16x8*)&Bs[(wn + j * 16 + fr) * 40 + fk];
#pragma unroll
        for (int i = 0; i < 4; ++i)
#pragma unroll
            for (int j = 0; j < 4; ++j)
                acc[i][j] = __builtin_amdgcn_mfma_f32_16x16x32_bf16(
                    af[i], bfr[j], acc[i][j], 0, 0, 0);
    }

    // Epilogue: C/D layout col=lane&15, row=quad*4+reg (verified m89/m91)
#pragma unroll
    for (int i = 0; i < 4; ++i) {
#pragma unroll
        for (int r = 0; r < 4; ++r) {
            int row = m0 + wm + i * 16 + fq * 4 + r;
#pragma unroll
            for (int j = 0; j < 4; ++j) {
                int col = n0 + wn + j * 16 + fr;
                if (col < N) {
                    float v = acc[i][j][r];
                    if (flags & 4) v += bias[col];
                    if (flags & 8) v = (v > 20.f) ? v : log1pf(__expf(v));
                    if (flags & 1) C[(size_t)row * ldc + col] = v;
                    if ((flags & 2) && col < nbmax)
                        Cb[(size_t)row * ldcb + col] = f2bf(v);
                }
            }
        }
    }
}

// ---------------------------------------------------------------------------
// Depthwise causal conv (width 4) + SiLU. Reads u fp32 (BL, DINNER),
// writes ucb bf16.
// ---------------------------------------------------------------------------
__global__ void conv_silu(const float* __restrict__ u, const float* __restrict__ cw,
                          const float* __restrict__ cb, ushort* __restrict__ ucb) {
    int idx = blockIdx.x * 256 + threadIdx.x;     // over BL*DINNER
    int d = idx & (DINNER - 1);
    int bl = idx >> 11;                            // DINNER = 2048 = 2^11
    int l = bl & (LL - 1);
    const float* up = u + (size_t)bl * DINNER + d;
    float4 w = ((const float4*)cw)[d];             // conv_w[d][0..3]
    float acc = cb[d];
    acc = fmaf(w.w, up[0], acc);
    if (l >= 1) acc = fmaf(w.z, up[-DINNER], acc);
    if (l >= 2) acc = fmaf(w.y, up[-2 * DINNER], acc);
    if (l >= 3) acc = fmaf(w.x, up[-3 * DINNER], acc);
    ucb[idx] = f2bf(acc / (1.f + __expf(-acc)));   // silu
}

// ---------------------------------------------------------------------------
// Chunked selective scan: one thread per (b, chunk, d), 16 n-states in regs.
// Coalesced delta/uc/z/y streams (lane = d); B/C rows are wave-uniform
// float4 broadcasts. Thread index: g = (b*NCHUNK + c)*DINNER + d.
// P/F layout: [c][ (b*DINNER+d)*16 + n ]  (plane stride PFPLANE).
// ---------------------------------------------------------------------------
__global__ __launch_bounds__(256) void scan_phase1(
    const float* __restrict__ delta, const float* __restrict__ xdbl,
    const ushort* __restrict__ ucb, const float* __restrict__ A_log,
    float* __restrict__ P, float* __restrict__ F)
{
    int g = blockIdx.x * 256 + threadIdx.x;
    int d = g & (DINNER - 1);
    int c = (g >> 11) & (NCHUNK - 1);
    int b = g >> 16;                               // 11 + 5 bits below

    float An[16], p[16], f[16];
    const float4* alp = (const float4*)(A_log + (size_t)d * DSTATE);
#pragma unroll
    for (int q = 0; q < 4; ++q) {
        float4 a = alp[q];
        An[q * 4 + 0] = -__expf(a.x); An[q * 4 + 1] = -__expf(a.y);
        An[q * 4 + 2] = -__expf(a.z); An[q * 4 + 3] = -__expf(a.w);
    }
#pragma unroll
    for (int n = 0; n < 16; ++n) { p[n] = 1.f; f[n] = 0.f; }

    size_t bl0 = (size_t)b * LL + (size_t)c * LCH;
    const float* dptr = delta + bl0 * DINNER + d;
    const ushort* uptr = ucb + bl0 * DINNER + d;
    const float* xptr = xdbl + bl0 * 96 + DTRANK;

#pragma unroll 2
    for (int l = 0; l < LCH; ++l) {
        float dv = dptr[(size_t)l * DINNER];
        float du = dv * bf2f(uptr[(size_t)l * DINNER]);
        float4 B0 = *(const float4*)(xptr + (size_t)l * 96);
        float4 B1 = *(const float4*)(xptr + (size_t)l * 96 + 4);
        float4 B2 = *(const float4*)(xptr + (size_t)l * 96 + 8);
        float4 B3 = *(const float4*)(xptr + (size_t)l * 96 + 12);
        float Bv[16] = {B0.x, B0.y, B0.z, B0.w, B1.x, B1.y, B1.z, B1.w,
                        B2.x, B2.y, B2.z, B2.w, B3.x, B3.y, B3.z, B3.w};
#pragma unroll
        for (int n = 0; n < 16; ++n) {
            float dA = __expf(dv * An[n]);
            f[n] = fmaf(dA, f[n], du * Bv[n]);
            p[n] *= dA;
        }
    }
    size_t o = (size_t)c * PFPLANE + ((size_t)(b * DINNER + d) << 4);
#pragma unroll
    for (int q = 0; q < 4; ++q) {
        *(float4*)(P + o + q * 4) = make_float4(p[q*4], p[q*4+1], p[q*4+2], p[q*4+3]);
        *(float4*)(F + o + q * 4) = make_float4(f[q*4], f[q*4+1], f[q*4+2], f[q*4+3]);
    }
}

// Phase 2: serial combine over chunks; Hin overwrites P in place
// (each slot is read once then written by the same thread).
__global__ __launch_bounds__(256) void scan_phase2(
    float* __restrict__ P, const float* __restrict__ F)
{
    int g = blockIdx.x * 256 + threadIdx.x;   // (b*DINNER+d)*16 + n
    float h = 0.f;
#pragma unroll
    for (int c = 0; c < NCHUNK; ++c) {
        size_t idx = (size_t)c * PFPLANE + g;
        float pv = P[idx];
        float fv = F[idx];
        P[idx] = h;                            // Hin for chunk c
        h = fmaf(pv, h, fv);
    }
}

// Phase 3: re-run chunk from Hin (=P), produce gated y written IN PLACE over
// z (same element, read-before-write; zy deliberately NOT restrict).
__global__ __launch_bounds__(256) void scan_phase3(
    const float* __restrict__ delta, const float* __restrict__ xdbl,
    const ushort* __restrict__ ucb, ushort* zy,
    const float* __restrict__ A_log, const float* __restrict__ Dp,
    const float* __restrict__ Hin)
{
    int g = blockIdx.x * 256 + threadIdx.x;
    int d = g & (DINNER - 1);
    int c = (g >> 11) & (NCHUNK - 1);
    int b = g >> 16;

    float An[16], h[16];
    const float4* alp = (const float4*)(A_log + (size_t)d * DSTATE);
#pragma unroll
    for (int q = 0; q < 4; ++q) {
        float4 a = alp[q];
        An[q * 4 + 0] = -__expf(a.x); An[q * 4 + 1] = -__expf(a.y);
        An[q * 4 + 2] = -__expf(a.z); An[q * 4 + 3] = -__expf(a.w);
    }
    size_t o = (size_t)c * PFPLANE + ((size_t)(b * DINNER + d) << 4);
#pragma unroll
    for (int q = 0; q < 4; ++q) {
        float4 hv = *(const float4*)(Hin + o + q * 4);
        h[q * 4 + 0] = hv.x; h[q * 4 + 1] = hv.y;
        h[q * 4 + 2] = hv.z; h[q * 4 + 3] = hv.w;
    }
    float Dd = Dp[d];

    size_t bl0 = (size_t)b * LL + (size_t)c * LCH;
    const float* dptr = delta + bl0 * DINNER + d;
    const ushort* uptr = ucb + bl0 * DINNER + d;
    ushort* zyptr = zy + bl0 * DINNER + d;
    const float* xptr = xdbl + bl0 * 96 + DTRANK;

#pragma unroll 2
    for (int l = 0; l < LCH; ++l) {
        float dv = dptr[(size_t)l * DINNER];
        float uv = bf2f(uptr[(size_t)l * DINNER]);
        float zv = bf2f(zyptr[(size_t)l * DINNER]);
        float du = dv * uv;
        float4 B0 = *(const float4*)(xptr + (size_t)l * 96);
        float4 B1 = *(const float4*)(xptr + (size_t)l * 96 + 4);
        float4 B2 = *(const float4*)(xptr + (size_t)l * 96 + 8);
        float4 B3 = *(const float4*)(xptr + (size_t)l * 96 + 12);
        float4 C0 = *(const float4*)(xptr + (size_t)l * 96 + 16);
        float4 C1 = *(const float4*)(xptr + (size_t)l * 96 + 20);
        float4 C2 = *(const float4*)(xptr + (size_t)l * 96 + 24);
        float4 C3 = *(const float4*)(xptr + (size_t)l * 96 + 28);
        float Bv[16] = {B0.x, B0.y, B0.z, B0.w, B1.x, B1.y, B1.z, B1.w,
                        B2.x, B2.y, B2.z, B2.w, B3.x, B3.y, B3.z, B3.w};
        float Cv[16] = {C0.x, C0.y, C0.z, C0.w, C1.x, C1.y, C1.z, C1.w,
                        C2.x, C2.y, C2.z, C2.w, C3.x, C3.y, C3.z, C3.w};
        float y = 0.f;
#pragma unroll
        for (int n = 0; n < 16; ++n) {
            float dA = __expf(dv * An[n]);
            h[n] = fmaf(dA, h[n], du * Bv[n]);
            y = fmaf(h[n], Cv[n], y);
        }
        float sz = zv / (1.f + __expf(-zv));
        zyptr[(size_t)l * DINNER] = f2bf((y + uv * Dd) * sz);
    }
}

// ---------------------------------------------------------------------------
// Tiled transpose: o2 (B*L, DMODEL) fp32 -> out (B, DMODEL, L)
// ---------------------------------------------------------------------------
__global__ void transpose_out(const float* __restrict__ o2, float* __restrict__ out) {
    __shared__ float tile[32][33];
    int b = blockIdx.z;
    int l0 = blockIdx.x * 32;
    int e0 = blockIdx.y * 32;
    int tx = threadIdx.x, ty = threadIdx.y;        // 32 x 8
    const float* ob = o2 + (size_t)b * LL * DMODEL;
#pragma unroll
    for (int j = 0; j < 32; j += 8)
        tile[ty + j][tx] = ob[(size_t)(l0 + ty + j) * DMODEL + e0 + tx];
    __syncthreads();
    float* outb = out + (size_t)b * DMODEL * LL;
#pragma unroll
    for (int j = 0; j < 32; j += 8)
        outb[(size_t)(e0 + ty + j) * LL + l0 + tx] = tile[tx][ty + j];
}

// ---------------------------------------------------------------------------
extern "C" void kernel_launch(void* const* d_in, const int* in_sizes, int n_in,
                              void* d_out, int out_size, void* d_ws, size_t ws_size,
                              hipStream_t stream) {
    const float* x         = (const float*)d_in[0];
    const float* in_proj_w = (const float*)d_in[1];
    const float* conv_w    = (const float*)d_in[2];
    const float* conv_b    = (const float*)d_in[3];
    const float* x_proj_w  = (const float*)d_in[4];
    const float* dt_proj_w = (const float*)d_in[5];
    const float* dt_proj_b = (const float*)d_in[6];
    const float* A_log     = (const float*)d_in[7];
    const float* Dp        = (const float*)d_in[8];
    const float* out_proj_w= (const float*)d_in[9];
    const float* proj_w    = (const float*)d_in[10];
    const float* proj_b    = (const float*)d_in[11];
    float* out = (float*)d_out;

    // Workspace layout (byte offsets), total ~179 MB:
    //  A [0,64M):    u fp32 -> delta fp32 -> {out1b bf16 @0, out2 fp32 @16M}
    //  B [64M,96M):  zb bf16 -> y (in place, scan_phase3)
    //  C [96M,128M): xtb bf16 -> ucb bf16
    //  D [128M,160M): P (16M, Hin in place) | F (16M)
    //  E [160M,163M): xdbl fp32 (8192x96)
    //  F [163M,164M): dtlow bf16 (8192x64)
    //  W [164M,~179M): bf16 weights: wip 8M | wxp | wdt | wop 4M | wpj 2M
    char* wsb = (char*)d_ws;
    float*  bufU  = (float*)(wsb);
    ushort* zb    = (ushort*)(wsb + ((size_t)64 << 20));
    ushort* xtb   = (ushort*)(wsb + ((size_t)96 << 20));
    ushort* ucb   = (ushort*)(wsb + ((size_t)96 << 20));
    float*  Pbuf  = (float*)(wsb + ((size_t)128 << 20));
    float*  Fbuf  = (float*)(wsb + ((size_t)144 << 20));
    float*  xdbl  = (float*)(wsb + ((size_t)160 << 20));
    ushort* dtlow = (ushort*)(wsb + ((size_t)163 << 20));
    ushort* wip   = (ushort*)(wsb + ((size_t)164 << 20));   // 4096x1024
    ushort* wxp   = wip + (size_t)4194304;                   // 96x2048
    ushort* wdt   = wxp + (size_t)196608;                    // 2048x64
    ushort* wop   = wdt + (size_t)131072;                    // 1024x2048
    ushort* wpj   = wop + (size_t)2097152;                   // 1024x1024
    float*  delta = bufU;
    ushort* ybf   = zb;                                      // y overwrites z
    ushort* out1b = (ushort*)(wsb);
    float*  out2  = (float*)(wsb + ((size_t)16 << 20));

    // 0) weight conversions fp32 -> bf16
    f32_to_bf16<<<dim3(4096), 256, 0, stream>>>(in_proj_w, wip, 1048576);
    f32_to_bf16<<<dim3(192),  256, 0, stream>>>(x_proj_w,  wxp, 49152);
    f32_to_bf16<<<dim3(128),  256, 0, stream>>>(dt_proj_w, wdt, 32768);
    f32_to_bf16<<<dim3(2048), 256, 0, stream>>>(out_proj_w, wop, 524288);
    f32_to_bf16<<<dim3(1024), 256, 0, stream>>>(proj_w,    wpj, 262144);

    // 1) x -> xtb (transpose + bf16)
    transpose_convert_x<<<dim3(LL / 32, DMODEL / 32, BB), dim3(32, 8), 0, stream>>>(x, xtb);

    // 2) in_proj: u half -> bufU fp32; z half -> zb bf16
    gemm_bf16<<<dim3(DINNER / 128, BL / 128), 256, 0, stream>>>(
        xtb, wip, bufU, nullptr, nullptr,
        BL, DINNER, DMODEL, DMODEL, DMODEL, DINNER, 0, 0, 1);
    gemm_bf16<<<dim3(DINNER / 128, BL / 128), 256, 0, stream>>>(
        xtb, wip + (size_t)DINNER * DMODEL, nullptr, zb, nullptr,
        BL, DINNER, DMODEL, DMODEL, DMODEL, 0, DINNER, DINNER, 2);

    // 3) depthwise conv + silu: ucb bf16 (overwrites xtb region - xtb dead)
    conv_silu<<<dim3(BL * DINNER / 256), 256, 0, stream>>>(bufU, conv_w, conv_b, ucb);

    // 4) x_proj: xdbl fp32 (full 96) + dtlow bf16 (cols 0..63)
    gemm_bf16<<<dim3(1, BL / 128), 256, 0, stream>>>(
        ucb, wxp, xdbl, dtlow, nullptr,
        BL, 96, DINNER, DINNER, DINNER, 96, DTRANK, DTRANK, 1 | 2);

    // 5) dt_proj + bias + softplus -> delta fp32 (overwrites u - dead)
    gemm_bf16<<<dim3(DINNER / 128, BL / 128), 256, 0, stream>>>(
        dtlow, wdt, delta, nullptr, dt_proj_b,
        BL, DINNER, DTRANK, DTRANK, DTRANK, DINNER, 0, 0, 1 | 4 | 8);

    // 6) chunked selective scan (one thread per (b,c,d), 16 n-states in regs)
    const int scan_threads = BB * NCHUNK * DINNER;               // 262144
    scan_phase1<<<dim3(scan_threads / 256), 256, 0, stream>>>(
        delta, xdbl, ucb, A_log, Pbuf, Fbuf);
    scan_phase2<<<dim3(PFPLANE / 256), 256, 0, stream>>>(Pbuf, Fbuf);
    scan_phase3<<<dim3(scan_threads / 256), 256, 0, stream>>>(
        delta, xdbl, ucb, zb, A_log, Dp, Pbuf);

    // 7) out_proj: out1b bf16 = y @ out_proj_w^T
    gemm_bf16<<<dim3(DMODEL / 128, BL / 128), 256, 0, stream>>>(
        ybf, wop, nullptr, out1b, nullptr,
        BL, DMODEL, DINNER, DINNER, DINNER, 0, DMODEL, DMODEL, 2);

    // 8) proj: out2 fp32 = out1b @ proj_w^T + proj_b
    gemm_bf16<<<dim3(DMODEL / 128, BL / 128), 256, 0, stream>>>(
        out1b, wpj, out2, nullptr, proj_b,
        BL, DMODEL, DMODEL, DMODEL, DMODEL, DMODEL, 0, 0, 1 | 4);

    // 9) out2 -> out (B, DMODEL, L)
    transpose_out<<<dim3(LL / 32, DMODEL / 32, BB), dim3(32, 8), 0, stream>>>(out2, out);
}

// Round 7
// 816.497 us; speedup vs baseline: 1.0510x; 1.0510x over previous
//
#include <hip/hip_runtime.h>
#include <hip/hip_bf16.h>
#include <math.h>

// Problem constants
#define BB 4
#define DMODEL 1024
#define LL 2048
#define DSTATE 16
#define DCONV 4
#define DINNER 2048
#define DTRANK 64
#define BL (BB * LL)          // 8192 rows
#define NCHUNK 16
#define LCH (LL / NCHUNK)     // 128
#define PFPLANE (BB * DINNER * DSTATE)   // 131072 floats per chunk-plane

typedef unsigned short ushort;
typedef __bf16 bf16x8 __attribute__((ext_vector_type(8)));
typedef float f32x4 __attribute__((ext_vector_type(4)));

__device__ inline ushort f2bf(float f) {
    unsigned int u = __float_as_uint(f);
    u += 0x7fffu + ((u >> 16) & 1u);           // round-to-nearest-even
    return (ushort)(u >> 16);
}
__device__ inline float bf2f(ushort h) {
    return __uint_as_float(((unsigned int)h) << 16);
}

// ---------------------------------------------------------------------------
// fp32 -> bf16 bulk convert (n4 = count/4)
// ---------------------------------------------------------------------------
__global__ void f32_to_bf16(const float* __restrict__ src, ushort* __restrict__ dst, int n4) {
    int i = blockIdx.x * 256 + threadIdx.x;
    if (i < n4) {
        float4 v = ((const float4*)src)[i];
        ushort4 o;
        o.x = f2bf(v.x); o.y = f2bf(v.y); o.z = f2bf(v.z); o.w = f2bf(v.w);
        ((ushort4*)dst)[i] = o;
    }
}

// ---------------------------------------------------------------------------
// x (B, DMODEL, L) fp32 -> xtb (B*L, DMODEL) bf16 (transpose + convert)
// ---------------------------------------------------------------------------
__global__ void transpose_convert_x(const float* __restrict__ x, ushort* __restrict__ xtb) {
    __shared__ float tile[32][33];
    int b = blockIdx.z;
    int l0 = blockIdx.x * 32;
    int d0 = blockIdx.y * 32;
    int tx = threadIdx.x, ty = threadIdx.y;       // 32 x 8
    const float* xb = x + (size_t)b * DMODEL * LL;
#pragma unroll
    for (int j = 0; j < 32; j += 8)
        tile[ty + j][tx] = xb[(size_t)(d0 + ty + j) * LL + l0 + tx];
    __syncthreads();
    ushort* xtbb = xtb + (size_t)b * LL * DMODEL;
#pragma unroll
    for (int j = 0; j < 32; j += 8)
        xtbb[(size_t)(l0 + ty + j) * DMODEL + d0 + tx] = f2bf(tile[tx][ty + j]);
}

// ---------------------------------------------------------------------------
// Merged in_proj GEMM: [u|z](BL x 4096) = xtb(BL x 1024) @ wip(4096 x 1024)^T
// u half (cols < 2048) -> fp32 bufU; z half -> bf16 zb. Block-uniform split.
// 128x128 tile, 4 waves, 4x4 16x16 MFMA per wave, K-tile 32.
// ---------------------------------------------------------------------------
__global__ __launch_bounds__(256) void gemm_inproj(
    const ushort* __restrict__ A, const ushort* __restrict__ Bw,
    float* __restrict__ U, ushort* __restrict__ Z)
{
    __shared__ ushort As[128 * 40];
    __shared__ ushort Bs[128 * 40];
    const int tid = threadIdx.x;
    const int m0 = blockIdx.y * 128;
    const int n0 = blockIdx.x * 128;
    const int srow = tid >> 2;
    const int sseg = (tid & 3) * 8;
    const int wave = tid >> 6;
    const int lane = tid & 63;
    const int wm = (wave >> 1) * 64;
    const int wn = (wave & 1) * 64;
    const int fr = lane & 15;
    const int fq = lane >> 4;
    const int fk = fq * 8;

    f32x4 acc[4][4];
#pragma unroll
    for (int i = 0; i < 4; ++i)
#pragma unroll
        for (int j = 0; j < 4; ++j)
            acc[i][j] = (f32x4)(0.0f);

    const ushort* Ap = A + (size_t)(m0 + srow) * DMODEL + sseg;
    const ushort* Bp = Bw + (size_t)(n0 + srow) * DMODEL + sseg;

    for (int k0 = 0; k0 < DMODEL; k0 += 32) {
        uint4 a0 = *(const uint4*)(Ap + k0);
        uint4 a1 = *(const uint4*)(Ap + (size_t)64 * DMODEL + k0);
        uint4 b0 = *(const uint4*)(Bp + k0);
        uint4 b1 = *(const uint4*)(Bp + (size_t)64 * DMODEL + k0);
        __syncthreads();
        *(uint4*)&As[srow * 40 + sseg] = a0;
        *(uint4*)&As[(srow + 64) * 40 + sseg] = a1;
        *(uint4*)&Bs[srow * 40 + sseg] = b0;
        *(uint4*)&Bs[(srow + 64) * 40 + sseg] = b1;
        __syncthreads();
        bf16x8 af[4], bfr[4];
#pragma unroll
        for (int i = 0; i < 4; ++i)
            af[i] = *(const bf16x8*)&As[(wm + i * 16 + fr) * 40 + fk];
#pragma unroll
        for (int j = 0; j < 4; ++j)
            bfr[j] = *(const bf16x8*)&Bs[(wn + j * 16 + fr) * 40 + fk];
#pragma unroll
        for (int i = 0; i < 4; ++i)
#pragma unroll
            for (int j = 0; j < 4; ++j)
                acc[i][j] = __builtin_amdgcn_mfma_f32_16x16x32_bf16(
                    af[i], bfr[j], acc[i][j], 0, 0, 0);
    }

    if (n0 < DINNER) {
#pragma unroll
        for (int i = 0; i < 4; ++i)
#pragma unroll
            for (int r = 0; r < 4; ++r) {
                int row = m0 + wm + i * 16 + fq * 4 + r;
#pragma unroll
                for (int j = 0; j < 4; ++j)
                    U[(size_t)row * DINNER + n0 + wn + j * 16 + fr] = acc[i][j][r];
            }
    } else {
#pragma unroll
        for (int i = 0; i < 4; ++i)
#pragma unroll
            for (int r = 0; r < 4; ++r) {
                int row = m0 + wm + i * 16 + fq * 4 + r;
#pragma unroll
                for (int j = 0; j < 4; ++j)
                    Z[(size_t)row * DINNER + (n0 - DINNER) + wn + j * 16 + fr] =
                        f2bf(acc[i][j][r]);
            }
    }
}

// ---------------------------------------------------------------------------
// bf16 MFMA GEMM: C(M,N) = A(M,K) @ Bw(N,K)^T, fp32 accumulate.
// flags: 1 = write fp32 C (ldc), 2 = write bf16 Cb (ldcb, col<nbmax),
//        4 = add bias[col] (fp32), 8 = softplus.
// ---------------------------------------------------------------------------
__global__ __launch_bounds__(256) void gemm_bf16(
    const ushort* __restrict__ A, const ushort* __restrict__ Bw,
    float* __restrict__ C, ushort* __restrict__ Cb,
    const float* __restrict__ bias,
    int M, int N, int K, int lda, int ldb, int ldc, int ldcb, int nbmax, int flags)
{
    __shared__ ushort As[128 * 40];
    __shared__ ushort Bs[128 * 40];
    const int tid = threadIdx.x;
    const int m0 = blockIdx.y * 128;
    const int n0 = blockIdx.x * 128;
    const int srow = tid >> 2;
    const int sseg = (tid & 3) * 8;
    const int wave = tid >> 6;
    const int lane = tid & 63;
    const int wm = (wave >> 1) * 64;
    const int wn = (wave & 1) * 64;
    const int fr = lane & 15;
    const int fq = lane >> 4;
    const int fk = fq * 8;

    f32x4 acc[4][4];
#pragma unroll
    for (int i = 0; i < 4; ++i)
#pragma unroll
        for (int j = 0; j < 4; ++j)
            acc[i][j] = (f32x4)(0.0f);

    const ushort* Ap = A + (size_t)(m0 + srow) * lda + sseg;
    const ushort* Bp = Bw + (size_t)(n0 + srow) * ldb + sseg;
    const bool bv0 = (n0 + srow) < N;
    const bool bv1 = (n0 + srow + 64) < N;

    for (int k0 = 0; k0 < K; k0 += 32) {
        uint4 a0 = *(const uint4*)(Ap + k0);
        uint4 a1 = *(const uint4*)(Ap + (size_t)64 * lda + k0);
        uint4 zz = make_uint4(0u, 0u, 0u, 0u);
        uint4 b0 = bv0 ? *(const uint4*)(Bp + k0) : zz;
        uint4 b1 = bv1 ? *(const uint4*)(Bp + (size_t)64 * ldb + k0) : zz;
        __syncthreads();
        *(uint4*)&As[srow * 40 + sseg] = a0;
        *(uint4*)&As[(srow + 64) * 40 + sseg] = a1;
        *(uint4*)&Bs[srow * 40 + sseg] = b0;
        *(uint4*)&Bs[(srow + 64) * 40 + sseg] = b1;
        __syncthreads();
        bf16x8 af[4], bfr[4];
#pragma unroll
        for (int i = 0; i < 4; ++i)
            af[i] = *(const bf16x8*)&As[(wm + i * 16 + fr) * 40 + fk];
#pragma unroll
        for (int j = 0; j < 4; ++j)
            bfr[j] = *(const bf16x8*)&Bs[(wn + j * 16 + fr) * 40 + fk];
#pragma unroll
        for (int i = 0; i < 4; ++i)
#pragma unroll
            for (int j = 0; j < 4; ++j)
                acc[i][j] = __builtin_amdgcn_mfma_f32_16x16x32_bf16(
                    af[i], bfr[j], acc[i][j], 0, 0, 0);
    }

#pragma unroll
    for (int i = 0; i < 4; ++i) {
#pragma unroll
        for (int r = 0; r < 4; ++r) {
            int row = m0 + wm + i * 16 + fq * 4 + r;
#pragma unroll
            for (int j = 0; j < 4; ++j) {
                int col = n0 + wn + j * 16 + fr;
                if (col < N) {
                    float v = acc[i][j][r];
                    if (flags & 4) v += bias[col];
                    if (flags & 8) v = (v > 20.f) ? v : log1pf(__expf(v));
                    if (flags & 1) C[(size_t)row * ldc + col] = v;
                    if ((flags & 2) && col < nbmax)
                        Cb[(size_t)row * ldcb + col] = f2bf(v);
                }
            }
        }
    }
}

// ---------------------------------------------------------------------------
// Depthwise causal conv (width 4) + SiLU. Reads u fp32 (BL, DINNER),
// writes ucb bf16.
// ---------------------------------------------------------------------------
__global__ void conv_silu(const float* __restrict__ u, const float* __restrict__ cw,
                          const float* __restrict__ cb, ushort* __restrict__ ucb) {
    int idx = blockIdx.x * 256 + threadIdx.x;     // over BL*DINNER
    int d = idx & (DINNER - 1);
    int bl = idx >> 11;                            // DINNER = 2048 = 2^11
    int l = bl & (LL - 1);
    const float* up = u + (size_t)bl * DINNER + d;
    float4 w = ((const float4*)cw)[d];             // conv_w[d][0..3]
    float acc = cb[d];
    acc = fmaf(w.w, up[0], acc);
    if (l >= 1) acc = fmaf(w.z, up[-DINNER], acc);
    if (l >= 2) acc = fmaf(w.y, up[-2 * DINNER], acc);
    if (l >= 3) acc = fmaf(w.x, up[-3 * DINNER], acc);
    ucb[idx] = f2bf(acc / (1.f + __expf(-acc)));   // silu
}

// ---------------------------------------------------------------------------
// Chunked selective scan. One thread per (b, chunk, d, n-half): 8 n-states
// in registers; the two halves of a d live in lanes (dlow | nh<<5), combined
// with one __shfl_xor(y,32). All streams coalesced / wave-broadcast.
// idx decomposition: lane = idx&63 -> dlow = lane&31, nh = lane>>5;
// dhigh = (idx>>6)&63; d = dhigh*32+dlow; c = (idx>>12)&15; b = idx>>16.
// P/F layout: [c][ (b*DINNER+d)*16 + n ] (plane stride PFPLANE floats).
// ---------------------------------------------------------------------------
__global__ __launch_bounds__(256) void scan_phase1(
    const float* __restrict__ delta, const float* __restrict__ xdbl,
    const ushort* __restrict__ ucb, const float* __restrict__ A_log,
    float* __restrict__ P, float* __restrict__ F)
{
    int idx = blockIdx.x * 256 + threadIdx.x;
    int lane = idx & 63;
    int nh = lane >> 5;
    int n0 = nh * 8;
    int d = (lane & 31) | (((idx >> 6) & 63) << 5);
    int c = (idx >> 12) & (NCHUNK - 1);
    int b = idx >> 16;

    float An[8], p[8], f[8];
    const float4* alp = (const float4*)(A_log + (size_t)d * DSTATE + n0);
#pragma unroll
    for (int q = 0; q < 2; ++q) {
        float4 a = alp[q];
        An[q * 4 + 0] = -__expf(a.x); An[q * 4 + 1] = -__expf(a.y);
        An[q * 4 + 2] = -__expf(a.z); An[q * 4 + 3] = -__expf(a.w);
    }
#pragma unroll
    for (int n = 0; n < 8; ++n) { p[n] = 1.f; f[n] = 0.f; }

    size_t bl0 = (size_t)b * LL + (size_t)c * LCH;
    const float* dptr = delta + bl0 * DINNER + d;
    const ushort* uptr = ucb + bl0 * DINNER + d;
    const float* xptr = xdbl + bl0 * 96 + DTRANK + n0;

#pragma unroll 2
    for (int l = 0; l < LCH; ++l) {
        float dv = dptr[(size_t)l * DINNER];
        float du = dv * bf2f(uptr[(size_t)l * DINNER]);
        float4 B0 = *(const float4*)(xptr + (size_t)l * 96);
        float4 B1 = *(const float4*)(xptr + (size_t)l * 96 + 4);
        float Bv[8] = {B0.x, B0.y, B0.z, B0.w, B1.x, B1.y, B1.z, B1.w};
#pragma unroll
        for (int n = 0; n < 8; ++n) {
            float dA = __expf(dv * An[n]);
            f[n] = fmaf(dA, f[n], du * Bv[n]);
            p[n] *= dA;
        }
    }
    size_t o = (size_t)c * PFPLANE + ((size_t)(b * DINNER + d) << 4) + n0;
    *(float4*)(P + o)     = make_float4(p[0], p[1], p[2], p[3]);
    *(float4*)(P + o + 4) = make_float4(p[4], p[5], p[6], p[7]);
    *(float4*)(F + o)     = make_float4(f[0], f[1], f[2], f[3]);
    *(float4*)(F + o + 4) = make_float4(f[4], f[5], f[6], f[7]);
}

// Phase 2: serial combine over chunks; Hin overwrites P in place
// (each slot is read once then written by the same thread).
__global__ __launch_bounds__(256) void scan_phase2(
    float* __restrict__ P, const float* __restrict__ F)
{
    int g = blockIdx.x * 256 + threadIdx.x;   // (b*DINNER+d)*16 + n
    float h = 0.f;
#pragma unroll
    for (int c = 0; c < NCHUNK; ++c) {
        size_t idx = (size_t)c * PFPLANE + g;
        float pv = P[idx];
        float fv = F[idx];
        P[idx] = h;                            // Hin for chunk c
        h = fmaf(pv, h, fv);
    }
}

// Phase 3: re-run chunk from Hin (=P), produce gated y -> ybf (separate buf).
__global__ __launch_bounds__(256) void scan_phase3(
    const float* __restrict__ delta, const float* __restrict__ xdbl,
    const ushort* __restrict__ ucb, const ushort* __restrict__ zb,
    const float* __restrict__ A_log, const float* __restrict__ Dp,
    const float* __restrict__ Hin, ushort* __restrict__ ybf)
{
    int idx = blockIdx.x * 256 + threadIdx.x;
    int lane = idx & 63;
    int nh = lane >> 5;
    int n0 = nh * 8;
    int d = (lane & 31) | (((idx >> 6) & 63) << 5);
    int c = (idx >> 12) & (NCHUNK - 1);
    int b = idx >> 16;

    float An[8], h[8];
    const float4* alp = (const float4*)(A_log + (size_t)d * DSTATE + n0);
#pragma unroll
    for (int q = 0; q < 2; ++q) {
        float4 a = alp[q];
        An[q * 4 + 0] = -__expf(a.x); An[q * 4 + 1] = -__expf(a.y);
        An[q * 4 + 2] = -__expf(a.z); An[q * 4 + 3] = -__expf(a.w);
    }
    size_t o = (size_t)c * PFPLANE + ((size_t)(b * DINNER + d) << 4) + n0;
    {
        float4 h0 = *(const float4*)(Hin + o);
        float4 h1 = *(const float4*)(Hin + o + 4);
        h[0] = h0.x; h[1] = h0.y; h[2] = h0.z; h[3] = h0.w;
        h[4] = h1.x; h[5] = h1.y; h[6] = h1.z; h[7] = h1.w;
    }
    float Dd = Dp[d];

    size_t bl0 = (size_t)b * LL + (size_t)c * LCH;
    const float* dptr = delta + bl0 * DINNER + d;
    const ushort* uptr = ucb + bl0 * DINNER + d;
    const ushort* zptr = zb + bl0 * DINNER + d;
    const float* xptr = xdbl + bl0 * 96 + DTRANK + n0;
    ushort* yptr = ybf + bl0 * DINNER + d;

#pragma unroll 2
    for (int l = 0; l < LCH; ++l) {
        float dv = dptr[(size_t)l * DINNER];
        float uv = bf2f(uptr[(size_t)l * DINNER]);
        float zv = bf2f(zptr[(size_t)l * DINNER]);
        float du = dv * uv;
        float4 B0 = *(const float4*)(xptr + (size_t)l * 96);
        float4 B1 = *(const float4*)(xptr + (size_t)l * 96 + 4);
        float4 C0 = *(const float4*)(xptr + (size_t)l * 96 + 16);
        float4 C1 = *(const float4*)(xptr + (size_t)l * 96 + 20);
        float Bv[8] = {B0.x, B0.y, B0.z, B0.w, B1.x, B1.y, B1.z, B1.w};
        float Cv[8] = {C0.x, C0.y, C0.z, C0.w, C1.x, C1.y, C1.z, C1.w};
        float y = 0.f;
#pragma unroll
        for (int n = 0; n < 8; ++n) {
            float dA = __expf(dv * An[n]);
            h[n] = fmaf(dA, h[n], du * Bv[n]);
            y = fmaf(h[n], Cv[n], y);
        }
        y += __shfl_xor(y, 32);                // combine the two n-halves
        if (nh == 0) {
            float sz = zv / (1.f + __expf(-zv));
            yptr[(size_t)l * DINNER] = f2bf((y + uv * Dd) * sz);
        }
    }
}

// ---------------------------------------------------------------------------
// Tiled transpose: o2 (B*L, DMODEL) fp32 -> out (B, DMODEL, L)
// ---------------------------------------------------------------------------
__global__ void transpose_out(const float* __restrict__ o2, float* __restrict__ out) {
    __shared__ float tile[32][33];
    int b = blockIdx.z;
    int l0 = blockIdx.x * 32;
    int e0 = blockIdx.y * 32;
    int tx = threadIdx.x, ty = threadIdx.y;        // 32 x 8
    const float* ob = o2 + (size_t)b * LL * DMODEL;
#pragma unroll
    for (int j = 0; j < 32; j += 8)
        tile[ty + j][tx] = ob[(size_t)(l0 + ty + j) * DMODEL + e0 + tx];
    __syncthreads();
    float* outb = out + (size_t)b * DMODEL * LL;
#pragma unroll
    for (int j = 0; j < 32; j += 8)
        outb[(size_t)(e0 + ty + j) * LL + l0 + tx] = tile[tx][ty + j];
}

// ---------------------------------------------------------------------------
extern "C" void kernel_launch(void* const* d_in, const int* in_sizes, int n_in,
                              void* d_out, int out_size, void* d_ws, size_t ws_size,
                              hipStream_t stream) {
    const float* x         = (const float*)d_in[0];
    const float* in_proj_w = (const float*)d_in[1];
    const float* conv_w    = (const float*)d_in[2];
    const float* conv_b    = (const float*)d_in[3];
    const float* x_proj_w  = (const float*)d_in[4];
    const float* dt_proj_w = (const float*)d_in[5];
    const float* dt_proj_b = (const float*)d_in[6];
    const float* A_log     = (const float*)d_in[7];
    const float* Dp        = (const float*)d_in[8];
    const float* out_proj_w= (const float*)d_in[9];
    const float* proj_w    = (const float*)d_in[10];
    const float* proj_b    = (const float*)d_in[11];
    float* out = (float*)d_out;

    // Workspace layout (byte offsets), total ~197 MB:
    //  A [0,64M):    u fp32 -> delta fp32 -> {out1b bf16 @0, out2 fp32 @16M}
    //  B [64M,96M):  zb bf16
    //  C [96M,128M): xtb bf16 -> ucb bf16
    //  D [128M,160M):ybf bf16
    //  E [160M,169M): P (Hin in place) | [169M,178M): F
    //  F [178M,181M): xdbl fp32 | [181M,182M): dtlow bf16
    //  W [182M,~197M): bf16 weights: wip 8M | wxp | wdt | wop 4M | wpj 2M
    char* wsb = (char*)d_ws;
    float*  bufU  = (float*)(wsb);
    ushort* zb    = (ushort*)(wsb + ((size_t)64 << 20));
    ushort* xtb   = (ushort*)(wsb + ((size_t)96 << 20));
    ushort* ucb   = (ushort*)(wsb + ((size_t)96 << 20));
    ushort* ybf   = (ushort*)(wsb + ((size_t)128 << 20));
    float*  Pbuf  = (float*)(wsb + ((size_t)160 << 20));
    float*  Fbuf  = (float*)(wsb + ((size_t)169 << 20));
    float*  xdbl  = (float*)(wsb + ((size_t)178 << 20));
    ushort* dtlow = (ushort*)(wsb + ((size_t)181 << 20));
    ushort* wip   = (ushort*)(wsb + ((size_t)182 << 20));   // 4096x1024
    ushort* wxp   = wip + (size_t)4194304;                   // 96x2048
    ushort* wdt   = wxp + (size_t)196608;                    // 2048x64
    ushort* wop   = wdt + (size_t)131072;                    // 1024x2048
    ushort* wpj   = wop + (size_t)2097152;                   // 1024x1024
    float*  delta = bufU;
    ushort* out1b = (ushort*)(wsb);
    float*  out2  = (float*)(wsb + ((size_t)16 << 20));

    // 0) weight conversions fp32 -> bf16
    f32_to_bf16<<<dim3(4096), 256, 0, stream>>>(in_proj_w, wip, 1048576);
    f32_to_bf16<<<dim3(192),  256, 0, stream>>>(x_proj_w,  wxp, 49152);
    f32_to_bf16<<<dim3(128),  256, 0, stream>>>(dt_proj_w, wdt, 32768);
    f32_to_bf16<<<dim3(2048), 256, 0, stream>>>(out_proj_w, wop, 524288);
    f32_to_bf16<<<dim3(1024), 256, 0, stream>>>(proj_w,    wpj, 262144);

    // 1) x -> xtb (transpose + bf16)
    transpose_convert_x<<<dim3(LL / 32, DMODEL / 32, BB), dim3(32, 8), 0, stream>>>(x, xtb);

    // 2) in_proj (merged): u half -> bufU fp32; z half -> zb bf16
    gemm_inproj<<<dim3(2 * DINNER / 128, BL / 128), 256, 0, stream>>>(
        xtb, wip, bufU, zb);

    // 3) depthwise conv + silu: ucb bf16 (overwrites xtb region - xtb dead)
    conv_silu<<<dim3(BL * DINNER / 256), 256, 0, stream>>>(bufU, conv_w, conv_b, ucb);

    // 4) x_proj: xdbl fp32 (full 96) + dtlow bf16 (cols 0..63)
    gemm_bf16<<<dim3(1, BL / 128), 256, 0, stream>>>(
        ucb, wxp, xdbl, dtlow, nullptr,
        BL, 96, DINNER, DINNER, DINNER, 96, DTRANK, DTRANK, 1 | 2);

    // 5) dt_proj + bias + softplus -> delta fp32 (overwrites u - dead)
    gemm_bf16<<<dim3(DINNER / 128, BL / 128), 256, 0, stream>>>(
        dtlow, wdt, delta, nullptr, dt_proj_b,
        BL, DINNER, DTRANK, DTRANK, DTRANK, DINNER, 0, 0, 1 | 4 | 8);

    // 6) chunked selective scan (thread per (b,c,d,n-half), 8 states in regs)
    const int scan_threads = BB * NCHUNK * DINNER * 2;           // 262144
    scan_phase1<<<dim3(scan_threads / 256), 256, 0, stream>>>(
        delta, xdbl, ucb, A_log, Pbuf, Fbuf);
    scan_phase2<<<dim3(PFPLANE / 256), 256, 0, stream>>>(Pbuf, Fbuf);
    scan_phase3<<<dim3(scan_threads / 256), 256, 0, stream>>>(
        delta, xdbl, ucb, zb, A_log, Dp, Pbuf, ybf);

    // 7) out_proj: out1b bf16 = y @ out_proj_w^T
    gemm_bf16<<<dim3(DMODEL / 128, BL / 128), 256, 0, stream>>>(
        ybf, wop, nullptr, out1b, nullptr,
        BL, DMODEL, DINNER, DINNER, DINNER, 0, DMODEL, DMODEL, 2);

    // 8) proj: out2 fp32 = out1b @ proj_w^T + proj_b
    gemm_bf16<<<dim3(DMODEL / 128, BL / 128), 256, 0, stream>>>(
        out1b, wpj, out2, nullptr, proj_b,
        BL, DMODEL, DMODEL, DMODEL, DMODEL, DMODEL, 0, 0, 1 | 4);

    // 9) out2 -> out (B, DMODEL, L)
    transpose_out<<<dim3(LL / 32, DMODEL / 32, BB), dim3(32, 8), 0, stream>>>(out2, out);
}

// Round 8
// 716.552 us; speedup vs baseline: 1.1976x; 1.1395x over previous
//
#include <hip/hip_runtime.h>
#include <hip/hip_bf16.h>
#include <math.h>

// Problem constants
#define BB 4
#define DMODEL 1024
#define LL 2048
#define DSTATE 16
#define DCONV 4
#define DINNER 2048
#define DTRANK 64
#define BL (BB * LL)          // 8192 rows
#define NCHUNK 16
#define LCH (LL / NCHUNK)     // 128
#define PFPLANE (BB * DINNER * DSTATE)   // 131072 floats per chunk-plane

typedef unsigned short ushort;
typedef __bf16 bf16x8 __attribute__((ext_vector_type(8)));
typedef float f32x4 __attribute__((ext_vector_type(4)));

__device__ inline ushort f2bf(float f) {
    unsigned int u = __float_as_uint(f);
    u += 0x7fffu + ((u >> 16) & 1u);           // round-to-nearest-even
    return (ushort)(u >> 16);
}
__device__ inline float bf2f(ushort h) {
    return __uint_as_float(((unsigned int)h) << 16);
}
// Fast stable softplus: max(v,0) + log(1 + e^{-|v|}), HW exp/log (~8 VALU ops)
__device__ inline float softplus_fast(float v) {
    float e = __expf(-fabsf(v));
    return fmaxf(v, 0.f) + __logf(1.f + e);
}

// ---------------------------------------------------------------------------
// fp32 -> bf16 bulk convert (n4 = count/4)
// ---------------------------------------------------------------------------
__global__ void f32_to_bf16(const float* __restrict__ src, ushort* __restrict__ dst, int n4) {
    int i = blockIdx.x * 256 + threadIdx.x;
    if (i < n4) {
        float4 v = ((const float4*)src)[i];
        ushort4 o;
        o.x = f2bf(v.x); o.y = f2bf(v.y); o.z = f2bf(v.z); o.w = f2bf(v.w);
        ((ushort4*)dst)[i] = o;
    }
}

// ---------------------------------------------------------------------------
// x (B, DMODEL, L) fp32 -> xtb (B*L, DMODEL) bf16 (transpose + convert)
// ---------------------------------------------------------------------------
__global__ void transpose_convert_x(const float* __restrict__ x, ushort* __restrict__ xtb) {
    __shared__ float tile[32][33];
    int b = blockIdx.z;
    int l0 = blockIdx.x * 32;
    int d0 = blockIdx.y * 32;
    int tx = threadIdx.x, ty = threadIdx.y;       // 32 x 8
    const float* xb = x + (size_t)b * DMODEL * LL;
#pragma unroll
    for (int j = 0; j < 32; j += 8)
        tile[ty + j][tx] = xb[(size_t)(d0 + ty + j) * LL + l0 + tx];
    __syncthreads();
    ushort* xtbb = xtb + (size_t)b * LL * DMODEL;
#pragma unroll
    for (int j = 0; j < 32; j += 8)
        xtbb[(size_t)(l0 + ty + j) * DMODEL + d0 + tx] = f2bf(tile[tx][ty + j]);
}

// ---------------------------------------------------------------------------
// Merged in_proj GEMM: [u|z](BL x 4096) = xtb(BL x 1024) @ wip(4096 x 1024)^T
// u half (cols < 2048) -> fp32 bufU; z half -> bf16 zb. Block-uniform split.
// ---------------------------------------------------------------------------
__global__ __launch_bounds__(256) void gemm_inproj(
    const ushort* __restrict__ A, const ushort* __restrict__ Bw,
    float* __restrict__ U, ushort* __restrict__ Z)
{
    __shared__ ushort As[128 * 40];
    __shared__ ushort Bs[128 * 40];
    const int tid = threadIdx.x;
    const int m0 = blockIdx.y * 128;
    const int n0 = blockIdx.x * 128;
    const int srow = tid >> 2;
    const int sseg = (tid & 3) * 8;
    const int wave = tid >> 6;
    const int lane = tid & 63;
    const int wm = (wave >> 1) * 64;
    const int wn = (wave & 1) * 64;
    const int fr = lane & 15;
    const int fq = lane >> 4;
    const int fk = fq * 8;

    f32x4 acc[4][4];
#pragma unroll
    for (int i = 0; i < 4; ++i)
#pragma unroll
        for (int j = 0; j < 4; ++j)
            acc[i][j] = (f32x4)(0.0f);

    const ushort* Ap = A + (size_t)(m0 + srow) * DMODEL + sseg;
    const ushort* Bp = Bw + (size_t)(n0 + srow) * DMODEL + sseg;

    for (int k0 = 0; k0 < DMODEL; k0 += 32) {
        uint4 a0 = *(const uint4*)(Ap + k0);
        uint4 a1 = *(const uint4*)(Ap + (size_t)64 * DMODEL + k0);
        uint4 b0 = *(const uint4*)(Bp + k0);
        uint4 b1 = *(const uint4*)(Bp + (size_t)64 * DMODEL + k0);
        __syncthreads();
        *(uint4*)&As[srow * 40 + sseg] = a0;
        *(uint4*)&As[(srow + 64) * 40 + sseg] = a1;
        *(uint4*)&Bs[srow * 40 + sseg] = b0;
        *(uint4*)&Bs[(srow + 64) * 40 + sseg] = b1;
        __syncthreads();
        bf16x8 af[4], bfr[4];
#pragma unroll
        for (int i = 0; i < 4; ++i)
            af[i] = *(const bf16x8*)&As[(wm + i * 16 + fr) * 40 + fk];
#pragma unroll
        for (int j = 0; j < 4; ++j)
            bfr[j] = *(const bf16x8*)&Bs[(wn + j * 16 + fr) * 40 + fk];
#pragma unroll
        for (int i = 0; i < 4; ++i)
#pragma unroll
            for (int j = 0; j < 4; ++j)
                acc[i][j] = __builtin_amdgcn_mfma_f32_16x16x32_bf16(
                    af[i], bfr[j], acc[i][j], 0, 0, 0);
    }

    if (n0 < DINNER) {
#pragma unroll
        for (int i = 0; i < 4; ++i)
#pragma unroll
            for (int r = 0; r < 4; ++r) {
                int row = m0 + wm + i * 16 + fq * 4 + r;
#pragma unroll
                for (int j = 0; j < 4; ++j)
                    U[(size_t)row * DINNER + n0 + wn + j * 16 + fr] = acc[i][j][r];
            }
    } else {
#pragma unroll
        for (int i = 0; i < 4; ++i)
#pragma unroll
            for (int r = 0; r < 4; ++r) {
                int row = m0 + wm + i * 16 + fq * 4 + r;
#pragma unroll
                for (int j = 0; j < 4; ++j)
                    Z[(size_t)row * DINNER + (n0 - DINNER) + wn + j * 16 + fr] =
                        f2bf(acc[i][j][r]);
            }
    }
}

// ---------------------------------------------------------------------------
// bf16 MFMA GEMM: C(M,N) = A(M,K) @ Bw(N,K)^T, fp32 accumulate.
// flags: 1 = write fp32 C (ldc), 2 = write bf16 Cb (ldcb, col<nbmax),
//        4 = add bias[col] (fp32), 8 = softplus (fast HW-transcendental form).
// ---------------------------------------------------------------------------
__global__ __launch_bounds__(256) void gemm_bf16(
    const ushort* __restrict__ A, const ushort* __restrict__ Bw,
    float* __restrict__ C, ushort* __restrict__ Cb,
    const float* __restrict__ bias,
    int M, int N, int K, int lda, int ldb, int ldc, int ldcb, int nbmax, int flags)
{
    __shared__ ushort As[128 * 40];
    __shared__ ushort Bs[128 * 40];
    const int tid = threadIdx.x;
    const int m0 = blockIdx.y * 128;
    const int n0 = blockIdx.x * 128;
    const int srow = tid >> 2;
    const int sseg = (tid & 3) * 8;
    const int wave = tid >> 6;
    const int lane = tid & 63;
    const int wm = (wave >> 1) * 64;
    const int wn = (wave & 1) * 64;
    const int fr = lane & 15;
    const int fq = lane >> 4;
    const int fk = fq * 8;

    f32x4 acc[4][4];
#pragma unroll
    for (int i = 0; i < 4; ++i)
#pragma unroll
        for (int j = 0; j < 4; ++j)
            acc[i][j] = (f32x4)(0.0f);

    const ushort* Ap = A + (size_t)(m0 + srow) * lda + sseg;
    const ushort* Bp = Bw + (size_t)(n0 + srow) * ldb + sseg;
    const bool bv0 = (n0 + srow) < N;
    const bool bv1 = (n0 + srow + 64) < N;

    for (int k0 = 0; k0 < K; k0 += 32) {
        uint4 a0 = *(const uint4*)(Ap + k0);
        uint4 a1 = *(const uint4*)(Ap + (size_t)64 * lda + k0);
        uint4 zz = make_uint4(0u, 0u, 0u, 0u);
        uint4 b0 = bv0 ? *(const uint4*)(Bp + k0) : zz;
        uint4 b1 = bv1 ? *(const uint4*)(Bp + (size_t)64 * ldb + k0) : zz;
        __syncthreads();
        *(uint4*)&As[srow * 40 + sseg] = a0;
        *(uint4*)&As[(srow + 64) * 40 + sseg] = a1;
        *(uint4*)&Bs[srow * 40 + sseg] = b0;
        *(uint4*)&Bs[(srow + 64) * 40 + sseg] = b1;
        __syncthreads();
        bf16x8 af[4], bfr[4];
#pragma unroll
        for (int i = 0; i < 4; ++i)
            af[i] = *(const bf16x8*)&As[(wm + i * 16 + fr) * 40 + fk];
#pragma unroll
        for (int j = 0; j < 4; ++j)
            bfr[j] = *(const bf16x8*)&Bs[(wn + j * 16 + fr) * 40 + fk];
#pragma unroll
        for (int i = 0; i < 4; ++i)
#pragma unroll
            for (int j = 0; j < 4; ++j)
                acc[i][j] = __builtin_amdgcn_mfma_f32_16x16x32_bf16(
                    af[i], bfr[j], acc[i][j], 0, 0, 0);
    }

#pragma unroll
    for (int i = 0; i < 4; ++i) {
#pragma unroll
        for (int r = 0; r < 4; ++r) {
            int row = m0 + wm + i * 16 + fq * 4 + r;
#pragma unroll
            for (int j = 0; j < 4; ++j) {
                int col = n0 + wn + j * 16 + fr;
                if (col < N) {
                    float v = acc[i][j][r];
                    if (flags & 4) v += bias[col];
                    if (flags & 8) v = softplus_fast(v);
                    if (flags & 1) C[(size_t)row * ldc + col] = v;
                    if ((flags & 2) && col < nbmax)
                        Cb[(size_t)row * ldcb + col] = f2bf(v);
                }
            }
        }
    }
}

// ---------------------------------------------------------------------------
// Depthwise causal conv (width 4) + SiLU. Reads u fp32 (BL, DINNER),
// writes ucb bf16.
// ---------------------------------------------------------------------------
__global__ void conv_silu(const float* __restrict__ u, const float* __restrict__ cw,
                          const float* __restrict__ cb, ushort* __restrict__ ucb) {
    int idx = blockIdx.x * 256 + threadIdx.x;     // over BL*DINNER
    int d = idx & (DINNER - 1);
    int bl = idx >> 11;                            // DINNER = 2048 = 2^11
    int l = bl & (LL - 1);
    const float* up = u + (size_t)bl * DINNER + d;
    float4 w = ((const float4*)cw)[d];             // conv_w[d][0..3]
    float acc = cb[d];
    acc = fmaf(w.w, up[0], acc);
    if (l >= 1) acc = fmaf(w.z, up[-DINNER], acc);
    if (l >= 2) acc = fmaf(w.y, up[-2 * DINNER], acc);
    if (l >= 3) acc = fmaf(w.x, up[-3 * DINNER], acc);
    ucb[idx] = f2bf(acc / (1.f + __expf(-acc)));   // silu
}

// ---------------------------------------------------------------------------
// Chunked selective scan. One thread per (b, chunk, d, n-half): 8 n-states
// in registers; the two halves of a d live in lanes (dlow | nh<<5), combined
// with one __shfl_xor(y,32). All streams coalesced / wave-broadcast.
// ---------------------------------------------------------------------------
__global__ __launch_bounds__(256) void scan_phase1(
    const float* __restrict__ delta, const float* __restrict__ xdbl,
    const ushort* __restrict__ ucb, const float* __restrict__ A_log,
    float* __restrict__ P, float* __restrict__ F)
{
    int idx = blockIdx.x * 256 + threadIdx.x;
    int lane = idx & 63;
    int nh = lane >> 5;
    int n0 = nh * 8;
    int d = (lane & 31) | (((idx >> 6) & 63) << 5);
    int c = (idx >> 12) & (NCHUNK - 1);
    int b = idx >> 16;

    float An[8], p[8], f[8];
    const float4* alp = (const float4*)(A_log + (size_t)d * DSTATE + n0);
#pragma unroll
    for (int q = 0; q < 2; ++q) {
        float4 a = alp[q];
        An[q * 4 + 0] = -__expf(a.x); An[q * 4 + 1] = -__expf(a.y);
        An[q * 4 + 2] = -__expf(a.z); An[q * 4 + 3] = -__expf(a.w);
    }
#pragma unroll
    for (int n = 0; n < 8; ++n) { p[n] = 1.f; f[n] = 0.f; }

    size_t bl0 = (size_t)b * LL + (size_t)c * LCH;
    const float* dptr = delta + bl0 * DINNER + d;
    const ushort* uptr = ucb + bl0 * DINNER + d;
    const float* xptr = xdbl + bl0 * 96 + DTRANK + n0;

#pragma unroll 2
    for (int l = 0; l < LCH; ++l) {
        float dv = dptr[(size_t)l * DINNER];
        float du = dv * bf2f(uptr[(size_t)l * DINNER]);
        float4 B0 = *(const float4*)(xptr + (size_t)l * 96);
        float4 B1 = *(const float4*)(xptr + (size_t)l * 96 + 4);
        float Bv[8] = {B0.x, B0.y, B0.z, B0.w, B1.x, B1.y, B1.z, B1.w};
#pragma unroll
        for (int n = 0; n < 8; ++n) {
            float dA = __expf(dv * An[n]);
            f[n] = fmaf(dA, f[n], du * Bv[n]);
            p[n] *= dA;
        }
    }
    size_t o = (size_t)c * PFPLANE + ((size_t)(b * DINNER + d) << 4) + n0;
    *(float4*)(P + o)     = make_float4(p[0], p[1], p[2], p[3]);
    *(float4*)(P + o + 4) = make_float4(p[4], p[5], p[6], p[7]);
    *(float4*)(F + o)     = make_float4(f[0], f[1], f[2], f[3]);
    *(float4*)(F + o + 4) = make_float4(f[4], f[5], f[6], f[7]);
}

// Phase 2: serial combine over chunks; Hin overwrites P in place.
__global__ __launch_bounds__(256) void scan_phase2(
    float* __restrict__ P, const float* __restrict__ F)
{
    int g = blockIdx.x * 256 + threadIdx.x;   // (b*DINNER+d)*16 + n
    float h = 0.f;
#pragma unroll
    for (int c = 0; c < NCHUNK; ++c) {
        size_t idx = (size_t)c * PFPLANE + g;
        float pv = P[idx];
        float fv = F[idx];
        P[idx] = h;                            // Hin for chunk c
        h = fmaf(pv, h, fv);
    }
}

// Phase 3: re-run chunk from Hin (=P), produce gated y -> ybf.
__global__ __launch_bounds__(256) void scan_phase3(
    const float* __restrict__ delta, const float* __restrict__ xdbl,
    const ushort* __restrict__ ucb, const ushort* __restrict__ zb,
    const float* __restrict__ A_log, const float* __restrict__ Dp,
    const float* __restrict__ Hin, ushort* __restrict__ ybf)
{
    int idx = blockIdx.x * 256 + threadIdx.x;
    int lane = idx & 63;
    int nh = lane >> 5;
    int n0 = nh * 8;
    int d = (lane & 31) | (((idx >> 6) & 63) << 5);
    int c = (idx >> 12) & (NCHUNK - 1);
    int b = idx >> 16;

    float An[8], h[8];
    const float4* alp = (const float4*)(A_log + (size_t)d * DSTATE + n0);
#pragma unroll
    for (int q = 0; q < 2; ++q) {
        float4 a = alp[q];
        An[q * 4 + 0] = -__expf(a.x); An[q * 4 + 1] = -__expf(a.y);
        An[q * 4 + 2] = -__expf(a.z); An[q * 4 + 3] = -__expf(a.w);
    }
    size_t o = (size_t)c * PFPLANE + ((size_t)(b * DINNER + d) << 4) + n0;
    {
        float4 h0 = *(const float4*)(Hin + o);
        float4 h1 = *(const float4*)(Hin + o + 4);
        h[0] = h0.x; h[1] = h0.y; h[2] = h0.z; h[3] = h0.w;
        h[4] = h1.x; h[5] = h1.y; h[6] = h1.z; h[7] = h1.w;
    }
    float Dd = Dp[d];

    size_t bl0 = (size_t)b * LL + (size_t)c * LCH;
    const float* dptr = delta + bl0 * DINNER + d;
    const ushort* uptr = ucb + bl0 * DINNER + d;
    const ushort* zptr = zb + bl0 * DINNER + d;
    const float* xptr = xdbl + bl0 * 96 + DTRANK + n0;
    ushort* yptr = ybf + bl0 * DINNER + d;

#pragma unroll 2
    for (int l = 0; l < LCH; ++l) {
        float dv = dptr[(size_t)l * DINNER];
        float uv = bf2f(uptr[(size_t)l * DINNER]);
        float zv = bf2f(zptr[(size_t)l * DINNER]);
        float du = dv * uv;
        float4 B0 = *(const float4*)(xptr + (size_t)l * 96);
        float4 B1 = *(const float4*)(xptr + (size_t)l * 96 + 4);
        float4 C0 = *(const float4*)(xptr + (size_t)l * 96 + 16);
        float4 C1 = *(const float4*)(xptr + (size_t)l * 96 + 20);
        float Bv[8] = {B0.x, B0.y, B0.z, B0.w, B1.x, B1.y, B1.z, B1.w};
        float Cv[8] = {C0.x, C0.y, C0.z, C0.w, C1.x, C1.y, C1.z, C1.w};
        float y = 0.f;
#pragma unroll
        for (int n = 0; n < 8; ++n) {
            float dA = __expf(dv * An[n]);
            h[n] = fmaf(dA, h[n], du * Bv[n]);
            y = fmaf(h[n], Cv[n], y);
        }
        y += __shfl_xor(y, 32);                // combine the two n-halves
        if (nh == 0) {
            float sz = zv / (1.f + __expf(-zv));
            yptr[(size_t)l * DINNER] = f2bf((y + uv * Dd) * sz);
        }
    }
}

// ---------------------------------------------------------------------------
// Tiled transpose: o2 (B*L, DMODEL) fp32 -> out (B, DMODEL, L)
// ---------------------------------------------------------------------------
__global__ void transpose_out(const float* __restrict__ o2, float* __restrict__ out) {
    __shared__ float tile[32][33];
    int b = blockIdx.z;
    int l0 = blockIdx.x * 32;
    int e0 = blockIdx.y * 32;
    int tx = threadIdx.x, ty = threadIdx.y;        // 32 x 8
    const float* ob = o2 + (size_t)b * LL * DMODEL;
#pragma unroll
    for (int j = 0; j < 32; j += 8)
        tile[ty + j][tx] = ob[(size_t)(l0 + ty + j) * DMODEL + e0 + tx];
    __syncthreads();
    float* outb = out + (size_t)b * DMODEL * LL;
#pragma unroll
    for (int j = 0; j < 32; j += 8)
        outb[(size_t)(e0 + ty + j) * LL + l0 + tx] = tile[tx][ty + j];
}

// ---------------------------------------------------------------------------
extern "C" void kernel_launch(void* const* d_in, const int* in_sizes, int n_in,
                              void* d_out, int out_size, void* d_ws, size_t ws_size,
                              hipStream_t stream) {
    const float* x         = (const float*)d_in[0];
    const float* in_proj_w = (const float*)d_in[1];
    const float* conv_w    = (const float*)d_in[2];
    const float* conv_b    = (const float*)d_in[3];
    const float* x_proj_w  = (const float*)d_in[4];
    const float* dt_proj_w = (const float*)d_in[5];
    const float* dt_proj_b = (const float*)d_in[6];
    const float* A_log     = (const float*)d_in[7];
    const float* Dp        = (const float*)d_in[8];
    const float* out_proj_w= (const float*)d_in[9];
    const float* proj_w    = (const float*)d_in[10];
    const float* proj_b    = (const float*)d_in[11];
    float* out = (float*)d_out;

    // Workspace layout (byte offsets), total ~197 MB (same as R6).
    char* wsb = (char*)d_ws;
    float*  bufU  = (float*)(wsb);
    ushort* zb    = (ushort*)(wsb + ((size_t)64 << 20));
    ushort* xtb   = (ushort*)(wsb + ((size_t)96 << 20));
    ushort* ucb   = (ushort*)(wsb + ((size_t)96 << 20));
    ushort* ybf   = (ushort*)(wsb + ((size_t)128 << 20));
    float*  Pbuf  = (float*)(wsb + ((size_t)160 << 20));
    float*  Fbuf  = (float*)(wsb + ((size_t)169 << 20));
    float*  xdbl  = (float*)(wsb + ((size_t)178 << 20));
    ushort* dtlow = (ushort*)(wsb + ((size_t)181 << 20));
    ushort* wip   = (ushort*)(wsb + ((size_t)182 << 20));   // 4096x1024
    ushort* wxp   = wip + (size_t)4194304;                   // 96x2048
    ushort* wdt   = wxp + (size_t)196608;                    // 2048x64
    ushort* wop   = wdt + (size_t)131072;                    // 1024x2048
    ushort* wpj   = wop + (size_t)2097152;                   // 1024x1024
    float*  delta = bufU;
    ushort* out1b = (ushort*)(wsb);
    float*  out2  = (float*)(wsb + ((size_t)16 << 20));

    // 0) weight conversions fp32 -> bf16
    f32_to_bf16<<<dim3(4096), 256, 0, stream>>>(in_proj_w, wip, 1048576);
    f32_to_bf16<<<dim3(192),  256, 0, stream>>>(x_proj_w,  wxp, 49152);
    f32_to_bf16<<<dim3(128),  256, 0, stream>>>(dt_proj_w, wdt, 32768);
    f32_to_bf16<<<dim3(2048), 256, 0, stream>>>(out_proj_w, wop, 524288);
    f32_to_bf16<<<dim3(1024), 256, 0, stream>>>(proj_w,    wpj, 262144);

    // 1) x -> xtb (transpose + bf16)
    transpose_convert_x<<<dim3(LL / 32, DMODEL / 32, BB), dim3(32, 8), 0, stream>>>(x, xtb);

    // 2) in_proj (merged): u half -> bufU fp32; z half -> zb bf16
    gemm_inproj<<<dim3(2 * DINNER / 128, BL / 128), 256, 0, stream>>>(
        xtb, wip, bufU, zb);

    // 3) depthwise conv + silu: ucb bf16 (overwrites xtb region - xtb dead)
    conv_silu<<<dim3(BL * DINNER / 256), 256, 0, stream>>>(bufU, conv_w, conv_b, ucb);

    // 4) x_proj: xdbl fp32 (full 96) + dtlow bf16 (cols 0..63)
    gemm_bf16<<<dim3(1, BL / 128), 256, 0, stream>>>(
        ucb, wxp, xdbl, dtlow, nullptr,
        BL, 96, DINNER, DINNER, DINNER, 96, DTRANK, DTRANK, 1 | 2);

    // 5) dt_proj + bias + fast softplus -> delta fp32 (overwrites u - dead)
    gemm_bf16<<<dim3(DINNER / 128, BL / 128), 256, 0, stream>>>(
        dtlow, wdt, delta, nullptr, dt_proj_b,
        BL, DINNER, DTRANK, DTRANK, DTRANK, DINNER, 0, 0, 1 | 4 | 8);

    // 6) chunked selective scan (thread per (b,c,d,n-half), 8 states in regs)
    const int scan_threads = BB * NCHUNK * DINNER * 2;           // 262144
    scan_phase1<<<dim3(scan_threads / 256), 256, 0, stream>>>(
        delta, xdbl, ucb, A_log, Pbuf, Fbuf);
    scan_phase2<<<dim3(PFPLANE / 256), 256, 0, stream>>>(Pbuf, Fbuf);
    scan_phase3<<<dim3(scan_threads / 256), 256, 0, stream>>>(
        delta, xdbl, ucb, zb, A_log, Dp, Pbuf, ybf);

    // 7) out_proj: out1b bf16 = y @ out_proj_w^T
    gemm_bf16<<<dim3(DMODEL / 128, BL / 128), 256, 0, stream>>>(
        ybf, wop, nullptr, out1b, nullptr,
        BL, DMODEL, DINNER, DINNER, DINNER, 0, DMODEL, DMODEL, 2);

    // 8) proj: out2 fp32 = out1b @ proj_w^T + proj_b
    gemm_bf16<<<dim3(DMODEL / 128, BL / 128), 256, 0, stream>>>(
        out1b, wpj, out2, nullptr, proj_b,
        BL, DMODEL, DMODEL, DMODEL, DMODEL, DMODEL, 0, 0, 1 | 4);

    // 9) out2 -> out (B, DMODEL, L)
    transpose_out<<<dim3(LL / 32, DMODEL / 32, BB), dim3(32, 8), 0, stream>>>(out2, out);
}

// Round 9
// 702.878 us; speedup vs baseline: 1.2209x; 1.0195x over previous
//
#include <hip/hip_runtime.h>
#include <hip/hip_bf16.h>
#include <math.h>

// Problem constants
#define BB 4
#define DMODEL 1024
#define LL 2048
#define DSTATE 16
#define DCONV 4
#define DINNER 2048
#define DTRANK 64
#define BL (BB * LL)          // 8192 rows
#define NCHUNK 32
#define LCH (LL / NCHUNK)     // 64
#define PFPLANE (BB * DINNER * DSTATE)   // 131072 floats per chunk-plane

typedef unsigned short ushort;
typedef __bf16 bf16x8 __attribute__((ext_vector_type(8)));
typedef float f32x4 __attribute__((ext_vector_type(4)));

__device__ inline ushort f2bf(float f) {
    unsigned int u = __float_as_uint(f);
    u += 0x7fffu + ((u >> 16) & 1u);           // round-to-nearest-even
    return (ushort)(u >> 16);
}
__device__ inline float bf2f(ushort h) {
    return __uint_as_float(((unsigned int)h) << 16);
}
// Fast stable softplus: max(v,0) + log(1 + e^{-|v|}), HW exp/log (~8 VALU ops)
__device__ inline float softplus_fast(float v) {
    float e = __expf(-fabsf(v));
    return fmaxf(v, 0.f) + __logf(1.f + e);
}

// ---------------------------------------------------------------------------
// fp32 -> bf16 bulk convert (n4 = count/4)
// ---------------------------------------------------------------------------
__global__ void f32_to_bf16(const float* __restrict__ src, ushort* __restrict__ dst, int n4) {
    int i = blockIdx.x * 256 + threadIdx.x;
    if (i < n4) {
        float4 v = ((const float4*)src)[i];
        ushort4 o;
        o.x = f2bf(v.x); o.y = f2bf(v.y); o.z = f2bf(v.z); o.w = f2bf(v.w);
        ((ushort4*)dst)[i] = o;
    }
}

// ---------------------------------------------------------------------------
// x (B, DMODEL, L) fp32 -> xtb (B*L, DMODEL) bf16 (transpose + convert)
// ---------------------------------------------------------------------------
__global__ void transpose_convert_x(const float* __restrict__ x, ushort* __restrict__ xtb) {
    __shared__ float tile[32][33];
    int b = blockIdx.z;
    int l0 = blockIdx.x * 32;
    int d0 = blockIdx.y * 32;
    int tx = threadIdx.x, ty = threadIdx.y;       // 32 x 8
    const float* xb = x + (size_t)b * DMODEL * LL;
#pragma unroll
    for (int j = 0; j < 32; j += 8)
        tile[ty + j][tx] = xb[(size_t)(d0 + ty + j) * LL + l0 + tx];
    __syncthreads();
    ushort* xtbb = xtb + (size_t)b * LL * DMODEL;
#pragma unroll
    for (int j = 0; j < 32; j += 8)
        xtbb[(size_t)(l0 + ty + j) * DMODEL + d0 + tx] = f2bf(tile[tx][ty + j]);
}

// ---------------------------------------------------------------------------
// Merged in_proj GEMM: [u|z](BL x 4096) = xtb(BL x 1024) @ wip(4096 x 1024)^T
// u half (cols < 2048) -> fp32 bufU; z half -> bf16 zb. Block-uniform split.
// ---------------------------------------------------------------------------
__global__ __launch_bounds__(256) void gemm_inproj(
    const ushort* __restrict__ A, const ushort* __restrict__ Bw,
    float* __restrict__ U, ushort* __restrict__ Z)
{
    __shared__ ushort As[128 * 40];
    __shared__ ushort Bs[128 * 40];
    const int tid = threadIdx.x;
    const int m0 = blockIdx.y * 128;
    const int n0 = blockIdx.x * 128;
    const int srow = tid >> 2;
    const int sseg = (tid & 3) * 8;
    const int wave = tid >> 6;
    const int lane = tid & 63;
    const int wm = (wave >> 1) * 64;
    const int wn = (wave & 1) * 64;
    const int fr = lane & 15;
    const int fq = lane >> 4;
    const int fk = fq * 8;

    f32x4 acc[4][4];
#pragma unroll
    for (int i = 0; i < 4; ++i)
#pragma unroll
        for (int j = 0; j < 4; ++j)
            acc[i][j] = (f32x4)(0.0f);

    const ushort* Ap = A + (size_t)(m0 + srow) * DMODEL + sseg;
    const ushort* Bp = Bw + (size_t)(n0 + srow) * DMODEL + sseg;

    for (int k0 = 0; k0 < DMODEL; k0 += 32) {
        uint4 a0 = *(const uint4*)(Ap + k0);
        uint4 a1 = *(const uint4*)(Ap + (size_t)64 * DMODEL + k0);
        uint4 b0 = *(const uint4*)(Bp + k0);
        uint4 b1 = *(const uint4*)(Bp + (size_t)64 * DMODEL + k0);
        __syncthreads();
        *(uint4*)&As[srow * 40 + sseg] = a0;
        *(uint4*)&As[(srow + 64) * 40 + sseg] = a1;
        *(uint4*)&Bs[srow * 40 + sseg] = b0;
        *(uint4*)&Bs[(srow + 64) * 40 + sseg] = b1;
        __syncthreads();
        bf16x8 af[4], bfr[4];
#pragma unroll
        for (int i = 0; i < 4; ++i)
            af[i] = *(const bf16x8*)&As[(wm + i * 16 + fr) * 40 + fk];
#pragma unroll
        for (int j = 0; j < 4; ++j)
            bfr[j] = *(const bf16x8*)&Bs[(wn + j * 16 + fr) * 40 + fk];
#pragma unroll
        for (int i = 0; i < 4; ++i)
#pragma unroll
            for (int j = 0; j < 4; ++j)
                acc[i][j] = __builtin_amdgcn_mfma_f32_16x16x32_bf16(
                    af[i], bfr[j], acc[i][j], 0, 0, 0);
    }

    if (n0 < DINNER) {
#pragma unroll
        for (int i = 0; i < 4; ++i)
#pragma unroll
            for (int r = 0; r < 4; ++r) {
                int row = m0 + wm + i * 16 + fq * 4 + r;
#pragma unroll
                for (int j = 0; j < 4; ++j)
                    U[(size_t)row * DINNER + n0 + wn + j * 16 + fr] = acc[i][j][r];
            }
    } else {
#pragma unroll
        for (int i = 0; i < 4; ++i)
#pragma unroll
            for (int r = 0; r < 4; ++r) {
                int row = m0 + wm + i * 16 + fq * 4 + r;
#pragma unroll
                for (int j = 0; j < 4; ++j)
                    Z[(size_t)row * DINNER + (n0 - DINNER) + wn + j * 16 + fr] =
                        f2bf(acc[i][j][r]);
            }
    }
}

// ---------------------------------------------------------------------------
// bf16 MFMA GEMM: C(M,N) = A(M,K) @ Bw(N,K)^T, fp32 accumulate.
// flags: 1 = write fp32 C (ldc), 2 = write bf16 Cb (ldcb, col<nbmax),
//        4 = add bias[col] (fp32), 8 = softplus (fast HW-transcendental form).
// ---------------------------------------------------------------------------
__global__ __launch_bounds__(256) void gemm_bf16(
    const ushort* __restrict__ A, const ushort* __restrict__ Bw,
    float* __restrict__ C, ushort* __restrict__ Cb,
    const float* __restrict__ bias,
    int M, int N, int K, int lda, int ldb, int ldc, int ldcb, int nbmax, int flags)
{
    __shared__ ushort As[128 * 40];
    __shared__ ushort Bs[128 * 40];
    const int tid = threadIdx.x;
    const int m0 = blockIdx.y * 128;
    const int n0 = blockIdx.x * 128;
    const int srow = tid >> 2;
    const int sseg = (tid & 3) * 8;
    const int wave = tid >> 6;
    const int lane = tid & 63;
    const int wm = (wave >> 1) * 64;
    const int wn = (wave & 1) * 64;
    const int fr = lane & 15;
    const int fq = lane >> 4;
    const int fk = fq * 8;

    f32x4 acc[4][4];
#pragma unroll
    for (int i = 0; i < 4; ++i)
#pragma unroll
        for (int j = 0; j < 4; ++j)
            acc[i][j] = (f32x4)(0.0f);

    const ushort* Ap = A + (size_t)(m0 + srow) * lda + sseg;
    const ushort* Bp = Bw + (size_t)(n0 + srow) * ldb + sseg;
    const bool bv0 = (n0 + srow) < N;
    const bool bv1 = (n0 + srow + 64) < N;

    for (int k0 = 0; k0 < K; k0 += 32) {
        uint4 a0 = *(const uint4*)(Ap + k0);
        uint4 a1 = *(const uint4*)(Ap + (size_t)64 * lda + k0);
        uint4 zz = make_uint4(0u, 0u, 0u, 0u);
        uint4 b0 = bv0 ? *(const uint4*)(Bp + k0) : zz;
        uint4 b1 = bv1 ? *(const uint4*)(Bp + (size_t)64 * ldb + k0) : zz;
        __syncthreads();
        *(uint4*)&As[srow * 40 + sseg] = a0;
        *(uint4*)&As[(srow + 64) * 40 + sseg] = a1;
        *(uint4*)&Bs[srow * 40 + sseg] = b0;
        *(uint4*)&Bs[(srow + 64) * 40 + sseg] = b1;
        __syncthreads();
        bf16x8 af[4], bfr[4];
#pragma unroll
        for (int i = 0; i < 4; ++i)
            af[i] = *(const bf16x8*)&As[(wm + i * 16 + fr) * 40 + fk];
#pragma unroll
        for (int j = 0; j < 4; ++j)
            bfr[j] = *(const bf16x8*)&Bs[(wn + j * 16 + fr) * 40 + fk];
#pragma unroll
        for (int i = 0; i < 4; ++i)
#pragma unroll
            for (int j = 0; j < 4; ++j)
                acc[i][j] = __builtin_amdgcn_mfma_f32_16x16x32_bf16(
                    af[i], bfr[j], acc[i][j], 0, 0, 0);
    }

#pragma unroll
    for (int i = 0; i < 4; ++i) {
#pragma unroll
        for (int r = 0; r < 4; ++r) {
            int row = m0 + wm + i * 16 + fq * 4 + r;
#pragma unroll
            for (int j = 0; j < 4; ++j) {
                int col = n0 + wn + j * 16 + fr;
                if (col < N) {
                    float v = acc[i][j][r];
                    if (flags & 4) v += bias[col];
                    if (flags & 8) v = softplus_fast(v);
                    if (flags & 1) C[(size_t)row * ldc + col] = v;
                    if ((flags & 2) && col < nbmax)
                        Cb[(size_t)row * ldcb + col] = f2bf(v);
                }
            }
        }
    }
}

// ---------------------------------------------------------------------------
// Depthwise causal conv (width 4) + SiLU. Reads u fp32 (BL, DINNER),
// writes ucb bf16.
// ---------------------------------------------------------------------------
__global__ void conv_silu(const float* __restrict__ u, const float* __restrict__ cw,
                          const float* __restrict__ cb, ushort* __restrict__ ucb) {
    int idx = blockIdx.x * 256 + threadIdx.x;     // over BL*DINNER
    int d = idx & (DINNER - 1);
    int bl = idx >> 11;                            // DINNER = 2048 = 2^11
    int l = bl & (LL - 1);
    const float* up = u + (size_t)bl * DINNER + d;
    float4 w = ((const float4*)cw)[d];             // conv_w[d][0..3]
    float acc = cb[d];
    acc = fmaf(w.w, up[0], acc);
    if (l >= 1) acc = fmaf(w.z, up[-DINNER], acc);
    if (l >= 2) acc = fmaf(w.y, up[-2 * DINNER], acc);
    if (l >= 3) acc = fmaf(w.x, up[-3 * DINNER], acc);
    ucb[idx] = f2bf(acc / (1.f + __expf(-acc)));   // silu
}

// ---------------------------------------------------------------------------
// Chunked selective scan: one thread per (b, chunk, d), all 16 n-states in
// registers (measured best per-thread shape, R4). NCHUNK=32 -> 1024 blocks ->
// 4 blocks/CU for latency hiding. delta is bf16.
// Thread index: g -> d = g&2047, c = (g>>11)&31, b = g>>16.
// P/F layout: [c][ (b*DINNER+d)*16 + n ] (plane stride PFPLANE floats).
// ---------------------------------------------------------------------------
__global__ __launch_bounds__(256) void scan_phase1(
    const ushort* __restrict__ delta16, const float* __restrict__ xdbl,
    const ushort* __restrict__ ucb, const float* __restrict__ A_log,
    float* __restrict__ P, float* __restrict__ F)
{
    int g = blockIdx.x * 256 + threadIdx.x;
    int d = g & (DINNER - 1);
    int c = (g >> 11) & (NCHUNK - 1);
    int b = g >> 16;

    float An[16], p[16], f[16];
    const float4* alp = (const float4*)(A_log + (size_t)d * DSTATE);
#pragma unroll
    for (int q = 0; q < 4; ++q) {
        float4 a = alp[q];
        An[q * 4 + 0] = -__expf(a.x); An[q * 4 + 1] = -__expf(a.y);
        An[q * 4 + 2] = -__expf(a.z); An[q * 4 + 3] = -__expf(a.w);
    }
#pragma unroll
    for (int n = 0; n < 16; ++n) { p[n] = 1.f; f[n] = 0.f; }

    size_t bl0 = (size_t)b * LL + (size_t)c * LCH;
    const ushort* dptr = delta16 + bl0 * DINNER + d;
    const ushort* uptr = ucb + bl0 * DINNER + d;
    const float* xptr = xdbl + bl0 * 96 + DTRANK;

#pragma unroll 2
    for (int l = 0; l < LCH; ++l) {
        float dv = bf2f(dptr[(size_t)l * DINNER]);
        float du = dv * bf2f(uptr[(size_t)l * DINNER]);
        float4 B0 = *(const float4*)(xptr + (size_t)l * 96);
        float4 B1 = *(const float4*)(xptr + (size_t)l * 96 + 4);
        float4 B2 = *(const float4*)(xptr + (size_t)l * 96 + 8);
        float4 B3 = *(const float4*)(xptr + (size_t)l * 96 + 12);
        float Bv[16] = {B0.x, B0.y, B0.z, B0.w, B1.x, B1.y, B1.z, B1.w,
                        B2.x, B2.y, B2.z, B2.w, B3.x, B3.y, B3.z, B3.w};
#pragma unroll
        for (int n = 0; n < 16; ++n) {
            float dA = __expf(dv * An[n]);
            f[n] = fmaf(dA, f[n], du * Bv[n]);
            p[n] *= dA;
        }
    }
    size_t o = (size_t)c * PFPLANE + ((size_t)(b * DINNER + d) << 4);
#pragma unroll
    for (int q = 0; q < 4; ++q) {
        *(float4*)(P + o + q * 4) = make_float4(p[q*4], p[q*4+1], p[q*4+2], p[q*4+3]);
        *(float4*)(F + o + q * 4) = make_float4(f[q*4], f[q*4+1], f[q*4+2], f[q*4+3]);
    }
}

// Phase 2: serial combine over chunks; Hin overwrites P in place
// (each slot is read once then written by the same thread).
__global__ __launch_bounds__(256) void scan_phase2(
    float* __restrict__ P, const float* __restrict__ F)
{
    int g = blockIdx.x * 256 + threadIdx.x;   // (b*DINNER+d)*16 + n
    float h = 0.f;
#pragma unroll
    for (int c = 0; c < NCHUNK; ++c) {
        size_t idx = (size_t)c * PFPLANE + g;
        float pv = P[idx];
        float fv = F[idx];
        P[idx] = h;                            // Hin for chunk c
        h = fmaf(pv, h, fv);
    }
}

// Phase 3: re-run chunk from Hin (=P), produce gated y -> ybf.
// y accumulated in 4 partial chains to break the 16-deep fma dependency.
__global__ __launch_bounds__(256) void scan_phase3(
    const ushort* __restrict__ delta16, const float* __restrict__ xdbl,
    const ushort* __restrict__ ucb, const ushort* __restrict__ zb,
    const float* __restrict__ A_log, const float* __restrict__ Dp,
    const float* __restrict__ Hin, ushort* __restrict__ ybf)
{
    int g = blockIdx.x * 256 + threadIdx.x;
    int d = g & (DINNER - 1);
    int c = (g >> 11) & (NCHUNK - 1);
    int b = g >> 16;

    float An[16], h[16];
    const float4* alp = (const float4*)(A_log + (size_t)d * DSTATE);
#pragma unroll
    for (int q = 0; q < 4; ++q) {
        float4 a = alp[q];
        An[q * 4 + 0] = -__expf(a.x); An[q * 4 + 1] = -__expf(a.y);
        An[q * 4 + 2] = -__expf(a.z); An[q * 4 + 3] = -__expf(a.w);
    }
    size_t o = (size_t)c * PFPLANE + ((size_t)(b * DINNER + d) << 4);
#pragma unroll
    for (int q = 0; q < 4; ++q) {
        float4 hv = *(const float4*)(Hin + o + q * 4);
        h[q * 4 + 0] = hv.x; h[q * 4 + 1] = hv.y;
        h[q * 4 + 2] = hv.z; h[q * 4 + 3] = hv.w;
    }
    float Dd = Dp[d];

    size_t bl0 = (size_t)b * LL + (size_t)c * LCH;
    const ushort* dptr = delta16 + bl0 * DINNER + d;
    const ushort* uptr = ucb + bl0 * DINNER + d;
    const ushort* zptr = zb + bl0 * DINNER + d;
    const float* xptr = xdbl + bl0 * 96 + DTRANK;
    ushort* yptr = ybf + bl0 * DINNER + d;

#pragma unroll 2
    for (int l = 0; l < LCH; ++l) {
        float dv = bf2f(dptr[(size_t)l * DINNER]);
        float uv = bf2f(uptr[(size_t)l * DINNER]);
        float zv = bf2f(zptr[(size_t)l * DINNER]);
        float du = dv * uv;
        float4 B0 = *(const float4*)(xptr + (size_t)l * 96);
        float4 B1 = *(const float4*)(xptr + (size_t)l * 96 + 4);
        float4 B2 = *(const float4*)(xptr + (size_t)l * 96 + 8);
        float4 B3 = *(const float4*)(xptr + (size_t)l * 96 + 12);
        float4 C0 = *(const float4*)(xptr + (size_t)l * 96 + 16);
        float4 C1 = *(const float4*)(xptr + (size_t)l * 96 + 20);
        float4 C2 = *(const float4*)(xptr + (size_t)l * 96 + 24);
        float4 C3 = *(const float4*)(xptr + (size_t)l * 96 + 28);
        float Bv[16] = {B0.x, B0.y, B0.z, B0.w, B1.x, B1.y, B1.z, B1.w,
                        B2.x, B2.y, B2.z, B2.w, B3.x, B3.y, B3.z, B3.w};
        float Cv[16] = {C0.x, C0.y, C0.z, C0.w, C1.x, C1.y, C1.z, C1.w,
                        C2.x, C2.y, C2.z, C2.w, C3.x, C3.y, C3.z, C3.w};
        float y0 = 0.f, y1 = 0.f, y2 = 0.f, y3 = 0.f;
#pragma unroll
        for (int n = 0; n < 4; ++n) {
            float dA0 = __expf(dv * An[n]);
            float dA1 = __expf(dv * An[n + 4]);
            float dA2 = __expf(dv * An[n + 8]);
            float dA3 = __expf(dv * An[n + 12]);
            h[n]      = fmaf(dA0, h[n],      du * Bv[n]);
            h[n + 4]  = fmaf(dA1, h[n + 4],  du * Bv[n + 4]);
            h[n + 8]  = fmaf(dA2, h[n + 8],  du * Bv[n + 8]);
            h[n + 12] = fmaf(dA3, h[n + 12], du * Bv[n + 12]);
            y0 = fmaf(h[n],      Cv[n],      y0);
            y1 = fmaf(h[n + 4],  Cv[n + 4],  y1);
            y2 = fmaf(h[n + 8],  Cv[n + 8],  y2);
            y3 = fmaf(h[n + 12], Cv[n + 12], y3);
        }
        float y = (y0 + y1) + (y2 + y3);
        float sz = zv / (1.f + __expf(-zv));
        yptr[(size_t)l * DINNER] = f2bf((y + uv * Dd) * sz);
    }
}

// ---------------------------------------------------------------------------
// Tiled transpose: o2 (B*L, DMODEL) fp32 -> out (B, DMODEL, L)
// ---------------------------------------------------------------------------
__global__ void transpose_out(const float* __restrict__ o2, float* __restrict__ out) {
    __shared__ float tile[32][33];
    int b = blockIdx.z;
    int l0 = blockIdx.x * 32;
    int e0 = blockIdx.y * 32;
    int tx = threadIdx.x, ty = threadIdx.y;        // 32 x 8
    const float* ob = o2 + (size_t)b * LL * DMODEL;
#pragma unroll
    for (int j = 0; j < 32; j += 8)
        tile[ty + j][tx] = ob[(size_t)(l0 + ty + j) * DMODEL + e0 + tx];
    __syncthreads();
    float* outb = out + (size_t)b * DMODEL * LL;
#pragma unroll
    for (int j = 0; j < 32; j += 8)
        outb[(size_t)(e0 + ty + j) * LL + l0 + tx] = tile[tx][ty + j];
}

// ---------------------------------------------------------------------------
extern "C" void kernel_launch(void* const* d_in, const int* in_sizes, int n_in,
                              void* d_out, int out_size, void* d_ws, size_t ws_size,
                              hipStream_t stream) {
    const float* x         = (const float*)d_in[0];
    const float* in_proj_w = (const float*)d_in[1];
    const float* conv_w    = (const float*)d_in[2];
    const float* conv_b    = (const float*)d_in[3];
    const float* x_proj_w  = (const float*)d_in[4];
    const float* dt_proj_w = (const float*)d_in[5];
    const float* dt_proj_b = (const float*)d_in[6];
    const float* A_log     = (const float*)d_in[7];
    const float* Dp        = (const float*)d_in[8];
    const float* out_proj_w= (const float*)d_in[9];
    const float* proj_w    = (const float*)d_in[10];
    const float* proj_b    = (const float*)d_in[11];
    float* out = (float*)d_out;

    // Workspace layout (byte offsets), total ~179 MB:
    //  A [0,64M):  u fp32 -> { delta16 bf16 [0,32M) | P [32M,48M) | F [48M,64M) }
    //              -> after scan: { out2 fp32 [0,32M) | out1b bf16 [32M,48M) }
    //  B [64,96M):  zb bf16
    //  C [96,128M): xtb bf16 -> ucb bf16
    //  D [128,160M): ybf bf16
    //  E [160,163M): xdbl fp32 | [163,164M): dtlow bf16
    //  W [164M,~179M): bf16 weights: wip 8M | wxp | wdt | wop 4M | wpj 2M
    char* wsb = (char*)d_ws;
    float*  bufU    = (float*)(wsb);
    ushort* delta16 = (ushort*)(wsb);                        // [0,32M)
    float*  Pbuf    = (float*)(wsb + ((size_t)32 << 20));    // 16M (Hin in place)
    float*  Fbuf    = (float*)(wsb + ((size_t)48 << 20));    // 16M
    ushort* zb      = (ushort*)(wsb + ((size_t)64 << 20));
    ushort* xtb     = (ushort*)(wsb + ((size_t)96 << 20));
    ushort* ucb     = (ushort*)(wsb + ((size_t)96 << 20));
    ushort* ybf     = (ushort*)(wsb + ((size_t)128 << 20));
    float*  xdbl    = (float*)(wsb + ((size_t)160 << 20));
    ushort* dtlow   = (ushort*)(wsb + ((size_t)163 << 20));
    ushort* wip     = (ushort*)(wsb + ((size_t)164 << 20));  // 4096x1024
    ushort* wxp     = wip + (size_t)4194304;                 // 96x2048
    ushort* wdt     = wxp + (size_t)196608;                  // 2048x64
    ushort* wop     = wdt + (size_t)131072;                  // 1024x2048
    ushort* wpj     = wop + (size_t)2097152;                 // 1024x1024
    float*  out2    = (float*)(wsb);                         // after scan
    ushort* out1b   = (ushort*)(wsb + ((size_t)32 << 20));   // after scan

    // 0) weight conversions fp32 -> bf16
    f32_to_bf16<<<dim3(4096), 256, 0, stream>>>(in_proj_w, wip, 1048576);
    f32_to_bf16<<<dim3(192),  256, 0, stream>>>(x_proj_w,  wxp, 49152);
    f32_to_bf16<<<dim3(128),  256, 0, stream>>>(dt_proj_w, wdt, 32768);
    f32_to_bf16<<<dim3(2048), 256, 0, stream>>>(out_proj_w, wop, 524288);
    f32_to_bf16<<<dim3(1024), 256, 0, stream>>>(proj_w,    wpj, 262144);

    // 1) x -> xtb (transpose + bf16)
    transpose_convert_x<<<dim3(LL / 32, DMODEL / 32, BB), dim3(32, 8), 0, stream>>>(x, xtb);

    // 2) in_proj (merged): u half -> bufU fp32; z half -> zb bf16
    gemm_inproj<<<dim3(2 * DINNER / 128, BL / 128), 256, 0, stream>>>(
        xtb, wip, bufU, zb);

    // 3) depthwise conv + silu: ucb bf16 (overwrites xtb region - xtb dead)
    conv_silu<<<dim3(BL * DINNER / 256), 256, 0, stream>>>(bufU, conv_w, conv_b, ucb);

    // 4) x_proj: xdbl fp32 (full 96) + dtlow bf16 (cols 0..63)
    gemm_bf16<<<dim3(1, BL / 128), 256, 0, stream>>>(
        ucb, wxp, xdbl, dtlow, nullptr,
        BL, 96, DINNER, DINNER, DINNER, 96, DTRANK, DTRANK, 1 | 2);

    // 5) dt_proj + bias + fast softplus -> delta16 bf16 (overwrites u - dead)
    gemm_bf16<<<dim3(DINNER / 128, BL / 128), 256, 0, stream>>>(
        dtlow, wdt, nullptr, delta16, dt_proj_b,
        BL, DINNER, DTRANK, DTRANK, DTRANK, 0, DINNER, DINNER, 2 | 4 | 8);

    // 6) chunked selective scan (thread per (b,c,d), 16 states in regs)
    const int scan_threads = BB * NCHUNK * DINNER;               // 262144
    scan_phase1<<<dim3(scan_threads / 256), 256, 0, stream>>>(
        delta16, xdbl, ucb, A_log, Pbuf, Fbuf);
    scan_phase2<<<dim3(PFPLANE / 256), 256, 0, stream>>>(Pbuf, Fbuf);
    scan_phase3<<<dim3(scan_threads / 256), 256, 0, stream>>>(
        delta16, xdbl, ucb, zb, A_log, Dp, Pbuf, ybf);

    // 7) out_proj: out1b bf16 = y @ out_proj_w^T  (P/F/delta dead)
    gemm_bf16<<<dim3(DMODEL / 128, BL / 128), 256, 0, stream>>>(
        ybf, wop, nullptr, out1b, nullptr,
        BL, DMODEL, DINNER, DINNER, DINNER, 0, DMODEL, DMODEL, 2);

    // 8) proj: out2 fp32 = out1b @ proj_w^T + proj_b
    gemm_bf16<<<dim3(DMODEL / 128, BL / 128), 256, 0, stream>>>(
        out1b, wpj, out2, nullptr, proj_b,
        BL, DMODEL, DMODEL, DMODEL, DMODEL, DMODEL, 0, 0, 1 | 4);

    // 9) out2 -> out (B, DMODEL, L)
    transpose_out<<<dim3(LL / 32, DMODEL / 32, BB), dim3(32, 8), 0, stream>>>(out2, out);
}